// Round 18
// baseline (194.802 us; speedup 1.0000x reference)
//
#include <hip/hip_runtime.h>
#include <hip/hip_bf16.h>
#include <stdint.h>

// ---------------------------------------------------------------------------
// MultiHeadSelfAttention fused block, MI355X/gfx950, bf16 MFMA pipeline.
// B=4 S=2048 E=1024 H=16 D=64.
// R17: attn s-loop manually unrolled + reordered (T15 mechanism): order
// QK0-PACK0-QK1-PACK1-PV0-PV1 puts PACK1 (VALU) and PV0 (MFMA) in one
// scheduling region with no dependency -> cross-pipe overlap; QK1 likewise
// overlaps PACK0. Peak regs ~230 < 256 (launch_bounds(256,2)). Same ops,
// same barriers - pure reorder. GEMMs/cast/LN frozen at R16.
// ---------------------------------------------------------------------------

typedef short bf16x8_t __attribute__((ext_vector_type(8)));
typedef float f32x4_t __attribute__((ext_vector_type(4)));
typedef float f32x16_t __attribute__((ext_vector_type(16)));
typedef unsigned short u16x8_t __attribute__((ext_vector_type(8)));
typedef unsigned short u16x4_t __attribute__((ext_vector_type(4)));
typedef uint32_t u32x4_t __attribute__((ext_vector_type(4)));

#define DEV static __device__ __forceinline__

DEV unsigned short f2bf(float f) {  // RNE f32->bf16
  union { float f; uint32_t u; } v; v.f = f;
  uint32_t u = v.u;
  return (unsigned short)((u + 0x7fffu + ((u >> 16) & 1u)) >> 16);
}

DEV float b2f(unsigned short u) {
  union { uint32_t u; float f; } v; v.u = (uint32_t)u << 16; return v.f;
}

DEV uint32_t cvtpk(float a, float b) {  // packed {lo=a, hi=b} bf16, RNE
  uint32_t d;
  asm("v_cvt_pk_bf16_f32 %0, %1, %2" : "=v"(d) : "v"(a), "v"(b));
  return d;
}

// swap: a <- {a.lo_lanes, b.lo_lanes}, b <- {a.hi_lanes, b.hi_lanes}
DEV void plswap(uint32_t& a, uint32_t& b) {
  asm("v_permlane32_swap_b32 %0, %1" : "+v"(a), "+v"(b));
}

DEV float ex2(float x) { return __builtin_amdgcn_exp2f(x); }

template<int N> DEV void wait_vm() {  // counted vmem wait (T4)
  asm volatile("s_waitcnt vmcnt(%0)" :: "n"(N) : "memory");
}
DEV void bar() { __builtin_amdgcn_s_barrier(); }
DEV void sbar0() { __builtin_amdgcn_sched_barrier(0); }

typedef const __attribute__((address_space(1))) void* gp_t;
typedef __attribute__((address_space(3))) void* lp_t;

DEV void gld16(const void* g, void* l) {  // async global->LDS, 16B/lane
  __builtin_amdgcn_global_load_lds((gp_t)g, (lp_t)l, 16, 0, 0);
}

// ---------------------------------------------------------------------------
// Flat exact grid: X 4096 | Wq 512 | Wk 512 | Wv 512 | Wo 512 | mask 4 = 6148
__global__ __launch_bounds__(256) void cast_all(
    const float* __restrict__ x,
    const float* __restrict__ wq, const float* __restrict__ wk,
    const float* __restrict__ wv, const float* __restrict__ wo,
    const float* __restrict__ mask,
    unsigned short* __restrict__ xb,
    unsigned short* __restrict__ wqb, unsigned short* __restrict__ wkb,
    unsigned short* __restrict__ wvb, unsigned short* __restrict__ wob,
    float* __restrict__ emf, unsigned short* __restrict__ emb)
{
  const int cid = blockIdx.x;
  if (cid >= 6144) {  // EM = exp(mask): f32 (Vt fold) + bf16 (l-MFMA A-op)
    int i = ((cid - 6144) * 256 + (int)threadIdx.x) * 8;
    float4 a = *(const float4*)(mask + i);
    float4 b = *(const float4*)(mask + i + 4);
    const float C = 1.44269504f;
    float4 ea, eb;
    ea.x = ex2(a.x * C); ea.y = ex2(a.y * C); ea.z = ex2(a.z * C); ea.w = ex2(a.w * C);
    eb.x = ex2(b.x * C); eb.y = ex2(b.y * C); eb.z = ex2(b.z * C); eb.w = ex2(b.w * C);
    *(float4*)(emf + i) = ea;
    *(float4*)(emf + i + 4) = eb;
    u16x8_t o;
    o[0] = f2bf(ea.x); o[1] = f2bf(ea.y); o[2] = f2bf(ea.z); o[3] = f2bf(ea.w);
    o[4] = f2bf(eb.x); o[5] = f2bf(eb.y); o[6] = f2bf(eb.z); o[7] = f2bf(eb.w);
    *(u16x8_t*)(emb + i) = o;
    return;
  }
  const float* src; unsigned short* dst; int base;
  if (cid < 4096)      { src = x;  dst = xb;  base = cid; }
  else if (cid < 4608) { src = wq; dst = wqb; base = cid - 4096; }
  else if (cid < 5120) { src = wk; dst = wkb; base = cid - 4608; }
  else if (cid < 5632) { src = wv; dst = wvb; base = cid - 5120; }
  else                 { src = wo; dst = wob; base = cid - 5632; }
  int i = (base * 256 + (int)threadIdx.x) * 8;
  float4 a = *(const float4*)(src + i);
  float4 b = *(const float4*)(src + i + 4);
  u16x8_t o;
  o[0] = f2bf(a.x); o[1] = f2bf(a.y); o[2] = f2bf(a.z); o[3] = f2bf(a.w);
  o[4] = f2bf(b.x); o[5] = f2bf(b.y); o[6] = f2bf(b.z); o[7] = f2bf(b.w);
  *(u16x8_t*)(dst + i) = o;
}

// ---------------------------------------------------------------------------
// C[m,n] = sum_k A[m,k]*B[n,k]. BM=256 x BN tile, BK=64, 8 waves.
// BN=128: 3-buffer lead-2 (vmcnt 6). BN=256: 2-buffer lead-1 (vmcnt 8).
// XOR-swizzled LDS, M-fast grid (B-panel L2 reuse).
// MODE 0: QK proj, FLAT grid 256 + XCD-pair swizzle. out bf16 [B,H,S,D]
// MODE 2: Vt (A=Wv rows e, B=X rows (b,s)), out bf16 [B,H,D,S] * EM (resid=EMf)
// MODE 3: WO + bias + bf16 residual (residb=Xb) -> bf16 XR [M,N]
template<int MODE, int BN>
__global__ __launch_bounds__(512, 2) void gemm_bt(
    const unsigned short* __restrict__ A,
    const unsigned short* __restrict__ B0, const unsigned short* __restrict__ B1,
    const float* __restrict__ bias0, const float* __restrict__ bias1,
    const float* __restrict__ resid, const unsigned short* __restrict__ residb,
    unsigned short* __restrict__ o0, unsigned short* __restrict__ o1,
    float* __restrict__ of,
    int M, int N, int K)
{
  constexpr int NBUF = (BN == 128) ? 3 : 2;      // LDS buffers
  constexpr int BTB  = BN * 128;                 // B tile bytes
  constexpr int NJ   = BN / 64;                  // n-frags per wave
  constexpr int VMN  = (BN == 128) ? 6 : 8;      // steady-state vmcnt
  __shared__ __align__(16) char smem[NBUF * 32768 + NBUF * BTB];

  int z, m0, n0;
  if (MODE == 0) {
    const int id = blockIdx.x;
    const int l = (id & 7) * 32 + (id >> 3);
    z  = l & 1;
    m0 = ((l >> 1) & 31) * 256;
    n0 = (l >> 6) * BN;
  } else {
    z  = blockIdx.z;
    m0 = blockIdx.x * 256;
    n0 = blockIdx.y * BN;
  }
  const unsigned short* Bw = (MODE == 0 && z == 1) ? B1 : B0;
  const float* bias = (MODE == 0 && z == 1) ? bias1 : bias0;
  unsigned short* obf = (MODE == 0 && z == 1) ? o1 : o0;

  const int tid = threadIdx.x;
  const int lane = tid & 63;
  const int lr = lane & 15, lq = lane >> 4;
  const int wid = tid >> 6;            // 0..7
  const int wm = wid >> 2, wn = wid & 3;

  f32x4_t acc[8][NJ] = {};

  char* Abase = smem;
  char* Bbase = smem + NBUF * 32768;

  // stage K-tile kt (elements kt*64 .. +64) into buffer p
  auto STAGE = [&](int kt, int p) {
    char* ad = Abase + p * 32768;
    char* bd = Bbase + p * BTB;
    const int ke = kt * 64;
#pragma unroll
    for (int l = 0; l < 4; ++l) {      // A: 256 rows x 128 B
      int oo = tid * 16 + l * 8192;
      int row = oo >> 7, cb = oo & 127;
      int scb = cb ^ ((row & 7) << 4); // inverse swizzle on global source
      gld16((const char*)(A + (size_t)(m0 + row) * K + ke) + scb, ad + oo);
    }
#pragma unroll
    for (int l = 0; l < NJ; ++l) {     // B: BN rows x 128 B
      int oo = tid * 16 + l * 8192;
      int row = oo >> 7, cb = oo & 127;
      int scb = cb ^ ((row & 7) << 4);
      gld16((const char*)(Bw + (size_t)(n0 + row) * K + ke) + scb, bd + oo);
    }
  };

  const int NT = K >> 6;               // 16 for K=1024
  if (BN == 128) {
    STAGE(0, 0);
    STAGE(1, 1);
    wait_vm<VMN>();                    // tile 0 landed, tile 1 in flight
  } else {
    STAGE(0, 0);
    wait_vm<0>();
  }
  bar(); sbar0();

  for (int t = 0; t < NT; ++t) {
    const int p = (BN == 128) ? (t % 3) : (t & 1);
    if (BN == 128) {
      if (t + 2 < NT) { STAGE(t + 2, (t + 2) % 3); wait_vm<VMN>(); }
      else if (t == NT - 1) { wait_vm<0>(); }
      else { wait_vm<VMN>(); }
    } else {
      if (t + 1 < NT) { STAGE(t + 1, p ^ 1); wait_vm<VMN>(); }
      else { wait_vm<0>(); }
    }
    bar(); sbar0();

    const char* ab = Abase + p * 32768;
    const char* bb = Bbase + p * BTB;
#pragma unroll
    for (int ks = 0; ks < 2; ++ks) {
      bf16x8_t aF[8], bF[NJ];
#pragma unroll
      for (int i = 0; i < 8; ++i) {
        int row = wm * 128 + i * 16 + lr;
        int cc = (ks * 64 + lq * 16) ^ ((row & 7) << 4);
        aF[i] = *(const bf16x8_t*)(ab + row * 128 + cc);
      }
#pragma unroll
      for (int j = 0; j < NJ; ++j) {
        int row = wn * (16 * NJ) + j * 16 + lr;
        int cc = (ks * 64 + lq * 16) ^ ((row & 7) << 4);
        bF[j] = *(const bf16x8_t*)(bb + row * 128 + cc);
      }
#pragma unroll
      for (int i = 0; i < 8; ++i)
#pragma unroll
        for (int j = 0; j < NJ; ++j)
          acc[i][j] = __builtin_amdgcn_mfma_f32_16x16x32_bf16(aF[i], bF[j], acc[i][j], 0, 0, 0);
    }
    bar();   // all waves done reading buf p before it is restaged
  }

#pragma unroll
  for (int i = 0; i < 8; ++i) {
#pragma unroll
    for (int j = 0; j < NJ; ++j) {
      int n = n0 + wn * (16 * NJ) + j * 16 + lr;
#pragma unroll
      for (int r = 0; r < 4; ++r) {
        int m = m0 + wm * 128 + i * 16 + lq * 4 + r;
        float v = acc[i][j][r];
        if (MODE == 0) {
          // z=0 (Q): fold 1/sqrt(64) AND log2e so QK^T lands in log2 domain
          v = (v + bias[n]) * (z == 0 ? 0.18033688f : 1.0f);
          int b = m >> 11, s = m & 2047, h = n >> 6, d = n & 63;
          obf[(size_t)((b * 16 + h) * 2048 + s) * 64 + d] = f2bf(v);
        } else if (MODE == 2) {
          v = (v + bias[m]) * resid[n];  // resid = EMf, n = b*2048+s
          int b = n >> 11, s = n & 2047;
          obf[(size_t)(b * 1024 + m) * 2048 + s] = f2bf(v);
        } else {
          v = v + bias[n] + b2f(residb[(size_t)m * 1024 + n]);
          obf[(size_t)m * 1024 + n] = f2bf(v);   // bf16 XR for LN
        }
      }
    }
  }
}

// ---------------------------------------------------------------------------
// Flash attention, swapped-QK^T 32x32, max-free softmax, QBLK=256, KBLK=128.
// Grid 512, 256 threads (4 waves), wave owns 64 q (2 q-groups of 32).
// Counted-vmcnt pipeline. R17: manually unrolled s with T15 ordering
// QK0-PACK0-QK1-PACK1-PV0-PV1 (PACK1 VALU ∥ PV0 MFMA; QK1 ∥ PACK0).
__global__ __launch_bounds__(256, 2) void attn_kernel(
    const unsigned short* __restrict__ Qg, const unsigned short* __restrict__ Kg,
    const unsigned short* __restrict__ Vtg, const unsigned short* __restrict__ EMb,
    unsigned short* __restrict__ ctx)
{
  // smem: K[2][16384] | V[2][16384] | E[4096]; epilogue reuses 0..32K
  __shared__ __align__(16) char smem[69632];

  const int id = blockIdx.x;
  const int swz = (id & 7) * 64 + (id >> 3);  // bijective XCD swizzle (512/8)
  const int bh = swz >> 3, qt = swz & 7;
  const int b = bh >> 4, h = bh & 15;

  const int tid = threadIdx.x, lane = tid & 63, wid = tid >> 6;
  const int l31 = lane & 31, hi = lane >> 5;
  const int q0 = qt * 256 + wid * 64;
  const size_t head = (size_t)bh * (2048 * 64);
  const unsigned short* Kh = Kg + head;
  const unsigned short* Vh = Vtg + (size_t)bh * 64 * 2048;
  const unsigned short* emrow = EMb + (size_t)b * 2048;

  // Q B-fragments: col q = q0 + qg*32 + l31, d = ds*16 + 8*hi + j
  bf16x8_t qf[2][4];
#pragma unroll
  for (int qg = 0; qg < 2; ++qg) {
    const unsigned short* qp = Qg + head + (size_t)(q0 + qg * 32 + l31) * 64 + 8 * hi;
#pragma unroll
    for (int ds = 0; ds < 4; ++ds) qf[qg][ds] = *(const bf16x8_t*)(qp + ds * 16);
  }

  f32x16_t oaccA[2] = {}, oaccB[2] = {};  // O^T[d,q]: d 0-31 / 32-63 per qg
  f32x16_t lacc[2] = {};                  // denominators; read [0] at end

  const int sw_row = (l31 & 7) << 4;

  // stage 128-k chunk t into buffer p: exactly 8 gloads/thread (4 K + 4 V)
  auto STAGE = [&](int t, int p) {
    const int k0 = t * 128;
    char* kd = smem + p * 16384;
    char* vd = smem + 32768 + p * 16384;
#pragma unroll
    for (int r = 0; r < 4; ++r) {
      int oo = tid * 16 + r * 4096;
      {  // K: row = k (stride 128B), inverse swizzle on source
        int row = oo >> 7, cb = oo & 127;
        int scb = cb ^ ((row & 7) << 4);
        gld16((const char*)(Kh + (size_t)(k0 + row) * 64) + scb, kd + oo);
      }
      {  // V: row = d (stride 256B), inverse swizzle on source
        int row = oo >> 8, cb = oo & 255;
        int scb = cb ^ ((row & 7) << 4);
        gld16((const char*)(Vh + (size_t)row * 2048 + k0) + scb, vd + oo);
      }
    }
  };

  // prologue: whole EM row (4KB) + tile 0; full drain once
  gld16((const char*)(emrow + tid * 8), smem + 65536 + tid * 16);
  STAGE(0, 0);
  wait_vm<0>();
  bar(); sbar0();

  for (int t = 0; t < 16; ++t) {
    const int p = t & 1;
    if (t < 15) {
      STAGE(t + 1, p ^ 1);   // 8 loads in flight across the barrier
      wait_vm<8>();          // tile t's loads complete
    } else {
      wait_vm<0>();
    }
    bar(); sbar0();

    const char* kb = smem + p * 16384;
    const char* vb = smem + 32768 + p * 16384;
    const char* eb = smem + 65536 + t * 256;

    // ---- sub-tile helpers (compile-time s)
    auto QK = [&](int s, f32x16_t c0[2], f32x16_t c1[2]) {
      const char* kr0 = kb + s * 8192 + l31 * 128;
      const char* kr1 = kb + s * 8192 + (32 + l31) * 128;
      __builtin_amdgcn_s_setprio(1);
#pragma unroll
      for (int ds = 0; ds < 4; ++ds) {
        int cc = (ds * 32 + 16 * hi) ^ sw_row;
        bf16x8_t k0f = *(const bf16x8_t*)(kr0 + cc);
        bf16x8_t k1f = *(const bf16x8_t*)(kr1 + cc);
#pragma unroll
        for (int qg = 0; qg < 2; ++qg) {
          c0[qg] = __builtin_amdgcn_mfma_f32_32x32x16_bf16(k0f, qf[qg][ds], c0[qg], 0, 0, 0);
          c1[qg] = __builtin_amdgcn_mfma_f32_32x32x16_bf16(k1f, qf[qg][ds], c1[qg], 0, 0, 0);
        }
      }
      __builtin_amdgcn_s_setprio(0);
    };

    auto PACK = [&](const f32x16_t c0[2], const f32x16_t c1[2], bf16x8_t pf[2][4]) {
#pragma unroll
      for (int qg = 0; qg < 2; ++qg) {
        uint32_t w0[8], w1[8];
#pragma unroll
        for (int g = 0; g < 8; ++g) {
          const int i4 = (g & 3) * 4;
          if (g < 4) {
            w0[g] = cvtpk(ex2(c0[qg][i4]), ex2(c0[qg][i4 + 1]));
            w1[g] = cvtpk(ex2(c0[qg][i4 + 2]), ex2(c0[qg][i4 + 3]));
          } else {
            w0[g] = cvtpk(ex2(c1[qg][i4]), ex2(c1[qg][i4 + 1]));
            w1[g] = cvtpk(ex2(c1[qg][i4 + 2]), ex2(c1[qg][i4 + 3]));
          }
        }
#pragma unroll
        for (int ks = 0; ks < 4; ++ks) {
          const int gg = ((ks >> 1) << 2) + ((ks & 1) << 1);
          uint32_t a0 = w0[gg], b0 = w0[gg + 1];
          uint32_t a1 = w1[gg], b1 = w1[gg + 1];
          plswap(a0, b0);
          plswap(a1, b1);
          union { uint32_t u[4]; bf16x8_t v; } cv;
          cv.u[0] = a0; cv.u[1] = a1; cv.u[2] = b0; cv.u[3] = b1;
          pf[qg][ks] = cv.v;
        }
      }
    };

    auto PV = [&](int s, const bf16x8_t pf[2][4]) {
      const char* vr0 = vb + l31 * 256 + s * 128;
      const char* vr1 = vb + (32 + l31) * 256 + s * 128;
      const char* ebs = eb + s * 128;
      __builtin_amdgcn_s_setprio(1);
#pragma unroll
      for (int ks = 0; ks < 4; ++ks) {
        bf16x8_t ef = *(const bf16x8_t*)(ebs + ks * 32 + 16 * hi);
        int cc = (ks * 32 + 16 * hi) ^ sw_row;
        bf16x8_t v0f = *(const bf16x8_t*)(vr0 + cc);
        bf16x8_t v1f = *(const bf16x8_t*)(vr1 + cc);
#pragma unroll
        for (int qg = 0; qg < 2; ++qg) {
          oaccA[qg] = __builtin_amdgcn_mfma_f32_32x32x16_bf16(v0f, pf[qg][ks], oaccA[qg], 0, 0, 0);
          oaccB[qg] = __builtin_amdgcn_mfma_f32_32x32x16_bf16(v1f, pf[qg][ks], oaccB[qg], 0, 0, 0);
          lacc[qg]  = __builtin_amdgcn_mfma_f32_32x32x16_bf16(ef,  pf[qg][ks], lacc[qg],  0, 0, 0);
        }
      }
      __builtin_amdgcn_s_setprio(0);
    };

    // ---- T15 ordering: QK1 overlaps PACK0; PV0 overlaps PACK1
    f32x16_t cA0[2] = {}, cA1[2] = {};
    QK(0, cA0, cA1);
    bf16x8_t pfA[2][4];
    PACK(cA0, cA1, pfA);
    f32x16_t cB0[2] = {}, cB1[2] = {};
    QK(1, cB0, cB1);
    bf16x8_t pfB[2][4];
    PACK(cB0, cB1, pfB);
    PV(0, pfA);
    PV(1, pfB);

    bar();   // all waves done reading buf p before next STAGE overwrites it
  }

  // ---- epilogue: O^T -> LDS (swizzled) -> coalesced global store
  char* tb = smem + wid * 8192;  // per-wave 64q x 128B, reuses K buffers
#pragma unroll
  for (int qg = 0; qg < 2; ++qg) {
    const float inv = 1.0f / lacc[qg][0];
    char* trow = tb + qg * 4096 + l31 * 128;
    const int swq = (l31 & 7) << 4;
#pragma unroll
    for (int g2 = 0; g2 < 4; ++g2) {
      uint2 a0, a1;
      a0.x = cvtpk(oaccA[qg][4 * g2] * inv, oaccA[qg][4 * g2 + 1] * inv);
      a0.y = cvtpk(oaccA[qg][4 * g2 + 2] * inv, oaccA[qg][4 * g2 + 3] * inv);
      a1.x = cvtpk(oaccB[qg][4 * g2] * inv, oaccB[qg][4 * g2 + 1] * inv);
      a1.y = cvtpk(oaccB[qg][4 * g2 + 2] * inv, oaccB[qg][4 * g2 + 3] * inv);
      int d0 = 16 * g2 + 8 * hi;
      *(uint2*)(trow + ((d0) ^ swq)) = a0;
      *(uint2*)(trow + ((d0 + 64) ^ swq)) = a1;
    }
  }
#pragma unroll
  for (int half = 0; half < 2; ++half) {
    const int qq = half * 32 + (lane >> 1), cp = lane & 1;
    const char* trow = tb + qq * 128;
    const int swr = (qq & 7) << 4;
    unsigned short* op = ctx + ((size_t)(b * 2048 + q0 + qq)) * 1024 + h * 64 + cp * 32;
#pragma unroll
    for (int i = 0; i < 4; ++i) {
      int col = cp * 64 + i * 16;
      u32x4_t val = *(const u32x4_t*)(trow + (col ^ swr));
      *(u32x4_t*)(op + i * 8) = val;
    }
  }
}

// ---------------------------------------------------------------------------
// LN: read bf16 XR row (2KB), stats+normalize in f32, write f32 out.
__global__ __launch_bounds__(256) void ln_kernel(
    const unsigned short* __restrict__ xr, float* __restrict__ y,
    const float* __restrict__ g, const float* __restrict__ be)
{
  const int row = blockIdx.x, tid = threadIdx.x;
  const unsigned short* rp = xr + (size_t)row * 1024;
  u16x4_t xb = *(const u16x4_t*)(rp + tid * 4);
  float4 x;
  x.x = b2f(xb[0]); x.y = b2f(xb[1]); x.z = b2f(xb[2]); x.w = b2f(xb[3]);
  float s = x.x + x.y + x.z + x.w;
  float sq = x.x * x.x + x.y * x.y + x.z * x.z + x.w * x.w;
#pragma unroll
  for (int msk = 1; msk < 64; msk <<= 1) {
    s  += __shfl_xor(s, msk);
    sq += __shfl_xor(sq, msk);
  }
  __shared__ float red[8];
  const int wid = tid >> 6, lane = tid & 63;
  if (lane == 0) { red[wid] = s; red[4 + wid] = sq; }
  __syncthreads();
  s  = red[0] + red[1] + red[2] + red[3];
  sq = red[4] + red[5] + red[6] + red[7];
  float mu = s * (1.f / 1024.f);
  float var = sq * (1.f / 1024.f) - mu * mu;
  float rs = rsqrtf(var + 1e-12f);
  float4 gw = *(const float4*)(g + tid * 4);
  float4 bw = *(const float4*)(be + tid * 4);
  float4 o2;
  o2.x = (x.x - mu) * rs * gw.x + bw.x;
  o2.y = (x.y - mu) * rs * gw.y + bw.y;
  o2.z = (x.z - mu) * rs * gw.z + bw.z;
  o2.w = (x.w - mu) * rs * gw.w + bw.w;
  *(float4*)(y + (size_t)row * 1024 + tid * 4) = o2;
}

// ---------------------------------------------------------------------------
extern "C" void kernel_launch(void* const* d_in, const int* in_sizes, int n_in,
                              void* d_out, int out_size, void* d_ws, size_t ws_size,
                              hipStream_t stream)
{
  const float* x    = (const float*)d_in[0];
  const float* mask = (const float*)d_in[1];
  const float* wq   = (const float*)d_in[2];
  const float* bq   = (const float*)d_in[3];
  const float* wk   = (const float*)d_in[4];
  const float* bk   = (const float*)d_in[5];
  const float* wv   = (const float*)d_in[6];
  const float* bv   = (const float*)d_in[7];
  const float* wo   = (const float*)d_in[8];
  const float* bo   = (const float*)d_in[9];
  const float* lnw  = (const float*)d_in[10];
  const float* lnb  = (const float*)d_in[11];
  float* out = (float*)d_out;

  char* ws = (char*)d_ws;
  unsigned short* Xb  = (unsigned short*)(ws);                               // 16 MB
  unsigned short* Wqb = (unsigned short*)(ws + 16777216);                    // 2 MB
  unsigned short* Wkb = (unsigned short*)(ws + 16777216 + 2097152);
  unsigned short* Wvb = (unsigned short*)(ws + 16777216 + 2 * 2097152);
  unsigned short* Wob = (unsigned short*)(ws + 16777216 + 3 * 2097152);
  unsigned short* Qg  = (unsigned short*)(ws + 25165824);                    // [B,H,S,D]
  unsigned short* Kg  = (unsigned short*)(ws + 25165824 + 16777216);         // [B,H,S,D]
  unsigned short* Vtg = (unsigned short*)(ws + 25165824 + 2 * 16777216);     // [B,H,D,S]
  unsigned short* CTX = (unsigned short*)(ws + 25165824 + 3 * 16777216);     // [B,S,E]
  float*          EMf = (float*)(ws + 92274688);                             // 32 KB
  unsigned short* EMb = (unsigned short*)(ws + 92274688 + 32768);            // 16 KB
  unsigned short* XR  = Xb;   // bf16 WO+resid output (Xb dead after WO reads)

  cast_all<<<dim3(6148), 256, 0, stream>>>(x, wq, wk, wv, wo, mask,
                                           Xb, Wqb, Wkb, Wvb, Wob, EMf, EMb);
  gemm_bt<0, 256><<<dim3(256), 512, 0, stream>>>(Xb, Wqb, Wkb, bq, bk, nullptr, nullptr,
                                                 Qg, Kg, nullptr, 8192, 1024, 1024);
  gemm_bt<2, 128><<<dim3(4, 64, 1), 512, 0, stream>>>(Wvb, Xb, nullptr, bv, nullptr, EMf,
                                                      nullptr, Vtg, nullptr, nullptr,
                                                      1024, 8192, 1024);
  attn_kernel<<<dim3(512), 256, 0, stream>>>(Qg, Kg, Vtg, EMb, CTX);
  gemm_bt<3, 128><<<dim3(32, 8, 1), 512, 0, stream>>>(CTX, Wob, nullptr, bo, nullptr,
                                                      nullptr, Xb, XR, nullptr, nullptr,
                                                      8192, 1024, 1024);
  ln_kernel<<<dim3(8192), 256, 0, stream>>>(XR, out, lnw, lnb);
}

// Round 19
// 191.865 us; speedup vs baseline: 1.0153x; 1.0153x over previous
//
#include <hip/hip_runtime.h>
#include <hip/hip_bf16.h>
#include <stdint.h>

// ---------------------------------------------------------------------------
// MultiHeadSelfAttention fused block, MI355X/gfx950, bf16 MFMA pipeline.
// B=4 S=2048 E=1024 H=16 D=64.
// R18: attn reverted to R16/R13 exact (R17's two-c-set reorder spilled:
// +7MB scratch/dispatch, 86->93us; third failure mode confirming attn's
// 224-VGPR live set has no headroom - structure is a verified local optimum).
// Config: cast | QK 256x256 lead-1 (flat XCD-pair grid) | Vt 256x128 lead-2 |
// attn swapped-QK^T max-free (86.2us bit-stable) | WO+bf16resid->bf16 XR |
// LN bf16-in f32-out. Total 191.3us.
// ---------------------------------------------------------------------------

typedef short bf16x8_t __attribute__((ext_vector_type(8)));
typedef float f32x4_t __attribute__((ext_vector_type(4)));
typedef float f32x16_t __attribute__((ext_vector_type(16)));
typedef unsigned short u16x8_t __attribute__((ext_vector_type(8)));
typedef unsigned short u16x4_t __attribute__((ext_vector_type(4)));
typedef uint32_t u32x4_t __attribute__((ext_vector_type(4)));

#define DEV static __device__ __forceinline__

DEV unsigned short f2bf(float f) {  // RNE f32->bf16
  union { float f; uint32_t u; } v; v.f = f;
  uint32_t u = v.u;
  return (unsigned short)((u + 0x7fffu + ((u >> 16) & 1u)) >> 16);
}

DEV float b2f(unsigned short u) {
  union { uint32_t u; float f; } v; v.u = (uint32_t)u << 16; return v.f;
}

DEV uint32_t cvtpk(float a, float b) {  // packed {lo=a, hi=b} bf16, RNE
  uint32_t d;
  asm("v_cvt_pk_bf16_f32 %0, %1, %2" : "=v"(d) : "v"(a), "v"(b));
  return d;
}

// swap: a <- {a.lo_lanes, b.lo_lanes}, b <- {a.hi_lanes, b.hi_lanes}
DEV void plswap(uint32_t& a, uint32_t& b) {
  asm("v_permlane32_swap_b32 %0, %1" : "+v"(a), "+v"(b));
}

DEV float ex2(float x) { return __builtin_amdgcn_exp2f(x); }

template<int N> DEV void wait_vm() {  // counted vmem wait (T4)
  asm volatile("s_waitcnt vmcnt(%0)" :: "n"(N) : "memory");
}
DEV void bar() { __builtin_amdgcn_s_barrier(); }
DEV void sbar0() { __builtin_amdgcn_sched_barrier(0); }

typedef const __attribute__((address_space(1))) void* gp_t;
typedef __attribute__((address_space(3))) void* lp_t;

DEV void gld16(const void* g, void* l) {  // async global->LDS, 16B/lane
  __builtin_amdgcn_global_load_lds((gp_t)g, (lp_t)l, 16, 0, 0);
}

// ---------------------------------------------------------------------------
// Flat exact grid: X 4096 | Wq 512 | Wk 512 | Wv 512 | Wo 512 | mask 4 = 6148
__global__ __launch_bounds__(256) void cast_all(
    const float* __restrict__ x,
    const float* __restrict__ wq, const float* __restrict__ wk,
    const float* __restrict__ wv, const float* __restrict__ wo,
    const float* __restrict__ mask,
    unsigned short* __restrict__ xb,
    unsigned short* __restrict__ wqb, unsigned short* __restrict__ wkb,
    unsigned short* __restrict__ wvb, unsigned short* __restrict__ wob,
    float* __restrict__ emf, unsigned short* __restrict__ emb)
{
  const int cid = blockIdx.x;
  if (cid >= 6144) {  // EM = exp(mask): f32 (Vt fold) + bf16 (l-MFMA A-op)
    int i = ((cid - 6144) * 256 + (int)threadIdx.x) * 8;
    float4 a = *(const float4*)(mask + i);
    float4 b = *(const float4*)(mask + i + 4);
    const float C = 1.44269504f;
    float4 ea, eb;
    ea.x = ex2(a.x * C); ea.y = ex2(a.y * C); ea.z = ex2(a.z * C); ea.w = ex2(a.w * C);
    eb.x = ex2(b.x * C); eb.y = ex2(b.y * C); eb.z = ex2(b.z * C); eb.w = ex2(b.w * C);
    *(float4*)(emf + i) = ea;
    *(float4*)(emf + i + 4) = eb;
    u16x8_t o;
    o[0] = f2bf(ea.x); o[1] = f2bf(ea.y); o[2] = f2bf(ea.z); o[3] = f2bf(ea.w);
    o[4] = f2bf(eb.x); o[5] = f2bf(eb.y); o[6] = f2bf(eb.z); o[7] = f2bf(eb.w);
    *(u16x8_t*)(emb + i) = o;
    return;
  }
  const float* src; unsigned short* dst; int base;
  if (cid < 4096)      { src = x;  dst = xb;  base = cid; }
  else if (cid < 4608) { src = wq; dst = wqb; base = cid - 4096; }
  else if (cid < 5120) { src = wk; dst = wkb; base = cid - 4608; }
  else if (cid < 5632) { src = wv; dst = wvb; base = cid - 5120; }
  else                 { src = wo; dst = wob; base = cid - 5632; }
  int i = (base * 256 + (int)threadIdx.x) * 8;
  float4 a = *(const float4*)(src + i);
  float4 b = *(const float4*)(src + i + 4);
  u16x8_t o;
  o[0] = f2bf(a.x); o[1] = f2bf(a.y); o[2] = f2bf(a.z); o[3] = f2bf(a.w);
  o[4] = f2bf(b.x); o[5] = f2bf(b.y); o[6] = f2bf(b.z); o[7] = f2bf(b.w);
  *(u16x8_t*)(dst + i) = o;
}

// ---------------------------------------------------------------------------
// C[m,n] = sum_k A[m,k]*B[n,k]. BM=256 x BN tile, BK=64, 8 waves.
// BN=128: 3-buffer lead-2 (vmcnt 6). BN=256: 2-buffer lead-1 (vmcnt 8).
// XOR-swizzled LDS, M-fast grid (B-panel L2 reuse).
// MODE 0: QK proj, FLAT grid 256 + XCD-pair swizzle. out bf16 [B,H,S,D]
// MODE 2: Vt (A=Wv rows e, B=X rows (b,s)), out bf16 [B,H,D,S] * EM (resid=EMf)
// MODE 3: WO + bias + bf16 residual (residb=Xb) -> bf16 XR [M,N]
template<int MODE, int BN>
__global__ __launch_bounds__(512, 2) void gemm_bt(
    const unsigned short* __restrict__ A,
    const unsigned short* __restrict__ B0, const unsigned short* __restrict__ B1,
    const float* __restrict__ bias0, const float* __restrict__ bias1,
    const float* __restrict__ resid, const unsigned short* __restrict__ residb,
    unsigned short* __restrict__ o0, unsigned short* __restrict__ o1,
    float* __restrict__ of,
    int M, int N, int K)
{
  constexpr int NBUF = (BN == 128) ? 3 : 2;      // LDS buffers
  constexpr int BTB  = BN * 128;                 // B tile bytes
  constexpr int NJ   = BN / 64;                  // n-frags per wave
  constexpr int VMN  = (BN == 128) ? 6 : 8;      // steady-state vmcnt
  __shared__ __align__(16) char smem[NBUF * 32768 + NBUF * BTB];

  int z, m0, n0;
  if (MODE == 0) {
    const int id = blockIdx.x;
    const int l = (id & 7) * 32 + (id >> 3);
    z  = l & 1;
    m0 = ((l >> 1) & 31) * 256;
    n0 = (l >> 6) * BN;
  } else {
    z  = blockIdx.z;
    m0 = blockIdx.x * 256;
    n0 = blockIdx.y * BN;
  }
  const unsigned short* Bw = (MODE == 0 && z == 1) ? B1 : B0;
  const float* bias = (MODE == 0 && z == 1) ? bias1 : bias0;
  unsigned short* obf = (MODE == 0 && z == 1) ? o1 : o0;

  const int tid = threadIdx.x;
  const int lane = tid & 63;
  const int lr = lane & 15, lq = lane >> 4;
  const int wid = tid >> 6;            // 0..7
  const int wm = wid >> 2, wn = wid & 3;

  f32x4_t acc[8][NJ] = {};

  char* Abase = smem;
  char* Bbase = smem + NBUF * 32768;

  // stage K-tile kt (elements kt*64 .. +64) into buffer p
  auto STAGE = [&](int kt, int p) {
    char* ad = Abase + p * 32768;
    char* bd = Bbase + p * BTB;
    const int ke = kt * 64;
#pragma unroll
    for (int l = 0; l < 4; ++l) {      // A: 256 rows x 128 B
      int oo = tid * 16 + l * 8192;
      int row = oo >> 7, cb = oo & 127;
      int scb = cb ^ ((row & 7) << 4); // inverse swizzle on global source
      gld16((const char*)(A + (size_t)(m0 + row) * K + ke) + scb, ad + oo);
    }
#pragma unroll
    for (int l = 0; l < NJ; ++l) {     // B: BN rows x 128 B
      int oo = tid * 16 + l * 8192;
      int row = oo >> 7, cb = oo & 127;
      int scb = cb ^ ((row & 7) << 4);
      gld16((const char*)(Bw + (size_t)(n0 + row) * K + ke) + scb, bd + oo);
    }
  };

  const int NT = K >> 6;               // 16 for K=1024
  if (BN == 128) {
    STAGE(0, 0);
    STAGE(1, 1);
    wait_vm<VMN>();                    // tile 0 landed, tile 1 in flight
  } else {
    STAGE(0, 0);
    wait_vm<0>();
  }
  bar(); sbar0();

  for (int t = 0; t < NT; ++t) {
    const int p = (BN == 128) ? (t % 3) : (t & 1);
    if (BN == 128) {
      if (t + 2 < NT) { STAGE(t + 2, (t + 2) % 3); wait_vm<VMN>(); }
      else if (t == NT - 1) { wait_vm<0>(); }
      else { wait_vm<VMN>(); }
    } else {
      if (t + 1 < NT) { STAGE(t + 1, p ^ 1); wait_vm<VMN>(); }
      else { wait_vm<0>(); }
    }
    bar(); sbar0();

    const char* ab = Abase + p * 32768;
    const char* bb = Bbase + p * BTB;
#pragma unroll
    for (int ks = 0; ks < 2; ++ks) {
      bf16x8_t aF[8], bF[NJ];
#pragma unroll
      for (int i = 0; i < 8; ++i) {
        int row = wm * 128 + i * 16 + lr;
        int cc = (ks * 64 + lq * 16) ^ ((row & 7) << 4);
        aF[i] = *(const bf16x8_t*)(ab + row * 128 + cc);
      }
#pragma unroll
      for (int j = 0; j < NJ; ++j) {
        int row = wn * (16 * NJ) + j * 16 + lr;
        int cc = (ks * 64 + lq * 16) ^ ((row & 7) << 4);
        bF[j] = *(const bf16x8_t*)(bb + row * 128 + cc);
      }
#pragma unroll
      for (int i = 0; i < 8; ++i)
#pragma unroll
        for (int j = 0; j < NJ; ++j)
          acc[i][j] = __builtin_amdgcn_mfma_f32_16x16x32_bf16(aF[i], bF[j], acc[i][j], 0, 0, 0);
    }
    bar();   // all waves done reading buf p before it is restaged
  }

#pragma unroll
  for (int i = 0; i < 8; ++i) {
#pragma unroll
    for (int j = 0; j < NJ; ++j) {
      int n = n0 + wn * (16 * NJ) + j * 16 + lr;
#pragma unroll
      for (int r = 0; r < 4; ++r) {
        int m = m0 + wm * 128 + i * 16 + lq * 4 + r;
        float v = acc[i][j][r];
        if (MODE == 0) {
          // z=0 (Q): fold 1/sqrt(64) AND log2e so QK^T lands in log2 domain
          v = (v + bias[n]) * (z == 0 ? 0.18033688f : 1.0f);
          int b = m >> 11, s = m & 2047, h = n >> 6, d = n & 63;
          obf[(size_t)((b * 16 + h) * 2048 + s) * 64 + d] = f2bf(v);
        } else if (MODE == 2) {
          v = (v + bias[m]) * resid[n];  // resid = EMf, n = b*2048+s
          int b = n >> 11, s = n & 2047;
          obf[(size_t)(b * 1024 + m) * 2048 + s] = f2bf(v);
        } else {
          v = v + bias[n] + b2f(residb[(size_t)m * 1024 + n]);
          obf[(size_t)m * 1024 + n] = f2bf(v);   // bf16 XR for LN
        }
      }
    }
  }
}

// ---------------------------------------------------------------------------
// Flash attention, swapped-QK^T 32x32, max-free softmax, QBLK=256, KBLK=128.
// Grid 512, 256 threads (4 waves), wave owns 64 q (2 q-groups of 32).
// Counted-vmcnt pipeline; EM row (4KB) staged once in prologue. (R13 exact)
__global__ __launch_bounds__(256, 2) void attn_kernel(
    const unsigned short* __restrict__ Qg, const unsigned short* __restrict__ Kg,
    const unsigned short* __restrict__ Vtg, const unsigned short* __restrict__ EMb,
    unsigned short* __restrict__ ctx)
{
  // smem: K[2][16384] | V[2][16384] | E[4096]; epilogue reuses 0..32K
  __shared__ __align__(16) char smem[69632];

  const int id = blockIdx.x;
  const int swz = (id & 7) * 64 + (id >> 3);  // bijective XCD swizzle (512/8)
  const int bh = swz >> 3, qt = swz & 7;
  const int b = bh >> 4, h = bh & 15;

  const int tid = threadIdx.x, lane = tid & 63, wid = tid >> 6;
  const int l31 = lane & 31, hi = lane >> 5;
  const int q0 = qt * 256 + wid * 64;
  const size_t head = (size_t)bh * (2048 * 64);
  const unsigned short* Kh = Kg + head;
  const unsigned short* Vh = Vtg + (size_t)bh * 64 * 2048;
  const unsigned short* emrow = EMb + (size_t)b * 2048;

  // Q B-fragments: col q = q0 + qg*32 + l31, d = ds*16 + 8*hi + j
  bf16x8_t qf[2][4];
#pragma unroll
  for (int qg = 0; qg < 2; ++qg) {
    const unsigned short* qp = Qg + head + (size_t)(q0 + qg * 32 + l31) * 64 + 8 * hi;
#pragma unroll
    for (int ds = 0; ds < 4; ++ds) qf[qg][ds] = *(const bf16x8_t*)(qp + ds * 16);
  }

  f32x16_t oaccA[2] = {}, oaccB[2] = {};  // O^T[d,q]: d 0-31 / 32-63 per qg
  f32x16_t lacc[2] = {};                  // denominators; read [0] at end

  const int sw_row = (l31 & 7) << 4;

  // stage 128-k chunk t into buffer p: exactly 8 gloads/thread (4 K + 4 V)
  auto STAGE = [&](int t, int p) {
    const int k0 = t * 128;
    char* kd = smem + p * 16384;
    char* vd = smem + 32768 + p * 16384;
#pragma unroll
    for (int r = 0; r < 4; ++r) {
      int oo = tid * 16 + r * 4096;
      {  // K: row = k (stride 128B), inverse swizzle on source
        int row = oo >> 7, cb = oo & 127;
        int scb = cb ^ ((row & 7) << 4);
        gld16((const char*)(Kh + (size_t)(k0 + row) * 64) + scb, kd + oo);
      }
      {  // V: row = d (stride 256B), inverse swizzle on source
        int row = oo >> 8, cb = oo & 255;
        int scb = cb ^ ((row & 7) << 4);
        gld16((const char*)(Vh + (size_t)row * 2048 + k0) + scb, vd + oo);
      }
    }
  };

  // prologue: whole EM row (4KB) + tile 0; full drain once
  gld16((const char*)(emrow + tid * 8), smem + 65536 + tid * 16);
  STAGE(0, 0);
  wait_vm<0>();
  bar(); sbar0();

  for (int t = 0; t < 16; ++t) {
    const int p = t & 1;
    if (t < 15) {
      STAGE(t + 1, p ^ 1);   // 8 loads in flight across the barrier
      wait_vm<8>();          // tile t's loads complete
    } else {
      wait_vm<0>();
    }
    bar(); sbar0();

    const char* kb = smem + p * 16384;
    const char* vb = smem + 32768 + p * 16384;
    const char* eb = smem + 65536 + t * 256;

#pragma unroll
    for (int s = 0; s < 2; ++s) {  // two independent 64-k sub-tiles
      // ---- S^T = K . Q^T (log2 domain): c0 = k 0-31, c1 = k 32-63, per qg
      f32x16_t c0[2] = {}, c1[2] = {};
      {
        const char* kr0 = kb + s * 8192 + l31 * 128;
        const char* kr1 = kb + s * 8192 + (32 + l31) * 128;
        __builtin_amdgcn_s_setprio(1);
#pragma unroll
        for (int ds = 0; ds < 4; ++ds) {
          int cc = (ds * 32 + 16 * hi) ^ sw_row;
          bf16x8_t k0f = *(const bf16x8_t*)(kr0 + cc);
          bf16x8_t k1f = *(const bf16x8_t*)(kr1 + cc);
#pragma unroll
          for (int qg = 0; qg < 2; ++qg) {
            c0[qg] = __builtin_amdgcn_mfma_f32_32x32x16_bf16(k0f, qf[qg][ds], c0[qg], 0, 0, 0);
            c1[qg] = __builtin_amdgcn_mfma_f32_32x32x16_bf16(k1f, qf[qg][ds], c1[qg], 0, 0, 0);
          }
        }
        __builtin_amdgcn_s_setprio(0);
      }

      // ---- P = exp2(c) raw (max-free), pack bf16, permlane partner exchange
      bf16x8_t pf[2][4];
#pragma unroll
      for (int qg = 0; qg < 2; ++qg) {
        uint32_t w0[8], w1[8];
#pragma unroll
        for (int g = 0; g < 8; ++g) {
          const int i4 = (g & 3) * 4;
          if (g < 4) {
            w0[g] = cvtpk(ex2(c0[qg][i4]), ex2(c0[qg][i4 + 1]));
            w1[g] = cvtpk(ex2(c0[qg][i4 + 2]), ex2(c0[qg][i4 + 3]));
          } else {
            w0[g] = cvtpk(ex2(c1[qg][i4]), ex2(c1[qg][i4 + 1]));
            w1[g] = cvtpk(ex2(c1[qg][i4 + 2]), ex2(c1[qg][i4 + 3]));
          }
        }
#pragma unroll
        for (int ks = 0; ks < 4; ++ks) {
          const int gg = ((ks >> 1) << 2) + ((ks & 1) << 1);
          uint32_t a0 = w0[gg], b0 = w0[gg + 1];
          uint32_t a1 = w1[gg], b1 = w1[gg + 1];
          plswap(a0, b0);
          plswap(a1, b1);
          union { uint32_t u[4]; bf16x8_t v; } cv;
          cv.u[0] = a0; cv.u[1] = a1; cv.u[2] = b0; cv.u[3] = b1;
          pf[qg][ks] = cv.v;
        }
      }

      // ---- PV (O^T += Vt.P^T) and l (lacc += EM.P^T), frags shared across qg
      {
        const char* vr0 = vb + l31 * 256 + s * 128;
        const char* vr1 = vb + (32 + l31) * 256 + s * 128;
        const char* ebs = eb + s * 128;
        __builtin_amdgcn_s_setprio(1);
#pragma unroll
        for (int ks = 0; ks < 4; ++ks) {
          bf16x8_t ef = *(const bf16x8_t*)(ebs + ks * 32 + 16 * hi);
          int cc = (ks * 32 + 16 * hi) ^ sw_row;
          bf16x8_t v0f = *(const bf16x8_t*)(vr0 + cc);
          bf16x8_t v1f = *(const bf16x8_t*)(vr1 + cc);
#pragma unroll
          for (int qg = 0; qg < 2; ++qg) {
            oaccA[qg] = __builtin_amdgcn_mfma_f32_32x32x16_bf16(v0f, pf[qg][ks], oaccA[qg], 0, 0, 0);
            oaccB[qg] = __builtin_amdgcn_mfma_f32_32x32x16_bf16(v1f, pf[qg][ks], oaccB[qg], 0, 0, 0);
            lacc[qg]  = __builtin_amdgcn_mfma_f32_32x32x16_bf16(ef,  pf[qg][ks], lacc[qg],  0, 0, 0);
          }
        }
        __builtin_amdgcn_s_setprio(0);
      }
    }
    bar();   // all waves done reading buf p before next STAGE overwrites it
  }

  // ---- epilogue: O^T -> LDS (swizzled) -> coalesced global store
  char* tb = smem + wid * 8192;  // per-wave 64q x 128B, reuses K buffers
#pragma unroll
  for (int qg = 0; qg < 2; ++qg) {
    const float inv = 1.0f / lacc[qg][0];
    char* trow = tb + qg * 4096 + l31 * 128;
    const int swq = (l31 & 7) << 4;
#pragma unroll
    for (int g2 = 0; g2 < 4; ++g2) {
      uint2 a0, a1;
      a0.x = cvtpk(oaccA[qg][4 * g2] * inv, oaccA[qg][4 * g2 + 1] * inv);
      a0.y = cvtpk(oaccA[qg][4 * g2 + 2] * inv, oaccA[qg][4 * g2 + 3] * inv);
      a1.x = cvtpk(oaccB[qg][4 * g2] * inv, oaccB[qg][4 * g2 + 1] * inv);
      a1.y = cvtpk(oaccB[qg][4 * g2 + 2] * inv, oaccB[qg][4 * g2 + 3] * inv);
      int d0 = 16 * g2 + 8 * hi;
      *(uint2*)(trow + ((d0) ^ swq)) = a0;
      *(uint2*)(trow + ((d0 + 64) ^ swq)) = a1;
    }
  }
#pragma unroll
  for (int half = 0; half < 2; ++half) {
    const int qq = half * 32 + (lane >> 1), cp = lane & 1;
    const char* trow = tb + qq * 128;
    const int swr = (qq & 7) << 4;
    unsigned short* op = ctx + ((size_t)(b * 2048 + q0 + qq)) * 1024 + h * 64 + cp * 32;
#pragma unroll
    for (int i = 0; i < 4; ++i) {
      int col = cp * 64 + i * 16;
      u32x4_t val = *(const u32x4_t*)(trow + (col ^ swr));
      *(u32x4_t*)(op + i * 8) = val;
    }
  }
}

// ---------------------------------------------------------------------------
// LN: read bf16 XR row (2KB), stats+normalize in f32, write f32 out.
__global__ __launch_bounds__(256) void ln_kernel(
    const unsigned short* __restrict__ xr, float* __restrict__ y,
    const float* __restrict__ g, const float* __restrict__ be)
{
  const int row = blockIdx.x, tid = threadIdx.x;
  const unsigned short* rp = xr + (size_t)row * 1024;
  u16x4_t xb = *(const u16x4_t*)(rp + tid * 4);
  float4 x;
  x.x = b2f(xb[0]); x.y = b2f(xb[1]); x.z = b2f(xb[2]); x.w = b2f(xb[3]);
  float s = x.x + x.y + x.z + x.w;
  float sq = x.x * x.x + x.y * x.y + x.z * x.z + x.w * x.w;
#pragma unroll
  for (int msk = 1; msk < 64; msk <<= 1) {
    s  += __shfl_xor(s, msk);
    sq += __shfl_xor(sq, msk);
  }
  __shared__ float red[8];
  const int wid = tid >> 6, lane = tid & 63;
  if (lane == 0) { red[wid] = s; red[4 + wid] = sq; }
  __syncthreads();
  s  = red[0] + red[1] + red[2] + red[3];
  sq = red[4] + red[5] + red[6] + red[7];
  float mu = s * (1.f / 1024.f);
  float var = sq * (1.f / 1024.f) - mu * mu;
  float rs = rsqrtf(var + 1e-12f);
  float4 gw = *(const float4*)(g + tid * 4);
  float4 bw = *(const float4*)(be + tid * 4);
  float4 o2;
  o2.x = (x.x - mu) * rs * gw.x + bw.x;
  o2.y = (x.y - mu) * rs * gw.y + bw.y;
  o2.z = (x.z - mu) * rs * gw.z + bw.z;
  o2.w = (x.w - mu) * rs * gw.w + bw.w;
  *(float4*)(y + (size_t)row * 1024 + tid * 4) = o2;
}

// ---------------------------------------------------------------------------
extern "C" void kernel_launch(void* const* d_in, const int* in_sizes, int n_in,
                              void* d_out, int out_size, void* d_ws, size_t ws_size,
                              hipStream_t stream)
{
  const float* x    = (const float*)d_in[0];
  const float* mask = (const float*)d_in[1];
  const float* wq   = (const float*)d_in[2];
  const float* bq   = (const float*)d_in[3];
  const float* wk   = (const float*)d_in[4];
  const float* bk   = (const float*)d_in[5];
  const float* wv   = (const float*)d_in[6];
  const float* bv   = (const float*)d_in[7];
  const float* wo   = (const float*)d_in[8];
  const float* bo   = (const float*)d_in[9];
  const float* lnw  = (const float*)d_in[10];
  const float* lnb  = (const float*)d_in[11];
  float* out = (float*)d_out;

  char* ws = (char*)d_ws;
  unsigned short* Xb  = (unsigned short*)(ws);                               // 16 MB
  unsigned short* Wqb = (unsigned short*)(ws + 16777216);                    // 2 MB
  unsigned short* Wkb = (unsigned short*)(ws + 16777216 + 2097152);
  unsigned short* Wvb = (unsigned short*)(ws + 16777216 + 2 * 2097152);
  unsigned short* Wob = (unsigned short*)(ws + 16777216 + 3 * 2097152);
  unsigned short* Qg  = (unsigned short*)(ws + 25165824);                    // [B,H,S,D]
  unsigned short* Kg  = (unsigned short*)(ws + 25165824 + 16777216);         // [B,H,S,D]
  unsigned short* Vtg = (unsigned short*)(ws + 25165824 + 2 * 16777216);     // [B,H,D,S]
  unsigned short* CTX = (unsigned short*)(ws + 25165824 + 3 * 16777216);     // [B,S,E]
  float*          EMf = (float*)(ws + 92274688);                             // 32 KB
  unsigned short* EMb = (unsigned short*)(ws + 92274688 + 32768);            // 16 KB
  unsigned short* XR  = Xb;   // bf16 WO+resid output (Xb dead after WO reads)

  cast_all<<<dim3(6148), 256, 0, stream>>>(x, wq, wk, wv, wo, mask,
                                           Xb, Wqb, Wkb, Wvb, Wob, EMf, EMb);
  gemm_bt<0, 256><<<dim3(256), 512, 0, stream>>>(Xb, Wqb, Wkb, bq, bk, nullptr, nullptr,
                                                 Qg, Kg, nullptr, 8192, 1024, 1024);
  gemm_bt<2, 128><<<dim3(4, 64, 1), 512, 0, stream>>>(Wvb, Xb, nullptr, bv, nullptr, EMf,
                                                      nullptr, Vtg, nullptr, nullptr,
                                                      1024, 8192, 1024);
  attn_kernel<<<dim3(512), 256, 0, stream>>>(Qg, Kg, Vtg, EMb, CTX);
  gemm_bt<3, 128><<<dim3(32, 8, 1), 512, 0, stream>>>(CTX, Wob, nullptr, bo, nullptr,
                                                      nullptr, Xb, XR, nullptr, nullptr,
                                                      8192, 1024, 1024);
  ln_kernel<<<dim3(8192), 256, 0, stream>>>(XR, out, lnw, lnb);
}

// Round 20
// 187.519 us; speedup vs baseline: 1.0388x; 1.0232x over previous
//
#include <hip/hip_runtime.h>
#include <hip/hip_bf16.h>
#include <stdint.h>

// ---------------------------------------------------------------------------
// MultiHeadSelfAttention fused block, MI355X/gfx950, bf16 MFMA pipeline.
// B=4 S=2048 E=1024 H=16 D=64.
// R19: QK + Vt projections fused into ONE 512-block launch (they are
// mutually independent: disjoint outputs, shared read-only inputs).
// Blocks 0-255 = QK (flat XCD-pair grid, 256x256 lead-1); 256-511 = Vt
// (flat M-fast, 256x128 lead-2). Saves one launch gap + Vt backfills CUs
// during QK's retire tail. Bodies byte-equivalent to R18 (shared device fn).
// ---------------------------------------------------------------------------

typedef short bf16x8_t __attribute__((ext_vector_type(8)));
typedef float f32x4_t __attribute__((ext_vector_type(4)));
typedef float f32x16_t __attribute__((ext_vector_type(16)));
typedef unsigned short u16x8_t __attribute__((ext_vector_type(8)));
typedef unsigned short u16x4_t __attribute__((ext_vector_type(4)));
typedef uint32_t u32x4_t __attribute__((ext_vector_type(4)));

#define DEV static __device__ __forceinline__

DEV unsigned short f2bf(float f) {  // RNE f32->bf16
  union { float f; uint32_t u; } v; v.f = f;
  uint32_t u = v.u;
  return (unsigned short)((u + 0x7fffu + ((u >> 16) & 1u)) >> 16);
}

DEV float b2f(unsigned short u) {
  union { uint32_t u; float f; } v; v.u = (uint32_t)u << 16; return v.f;
}

DEV uint32_t cvtpk(float a, float b) {  // packed {lo=a, hi=b} bf16, RNE
  uint32_t d;
  asm("v_cvt_pk_bf16_f32 %0, %1, %2" : "=v"(d) : "v"(a), "v"(b));
  return d;
}

// swap: a <- {a.lo_lanes, b.lo_lanes}, b <- {a.hi_lanes, b.hi_lanes}
DEV void plswap(uint32_t& a, uint32_t& b) {
  asm("v_permlane32_swap_b32 %0, %1" : "+v"(a), "+v"(b));
}

DEV float ex2(float x) { return __builtin_amdgcn_exp2f(x); }

template<int N> DEV void wait_vm() {  // counted vmem wait (T4)
  asm volatile("s_waitcnt vmcnt(%0)" :: "n"(N) : "memory");
}
DEV void bar() { __builtin_amdgcn_s_barrier(); }
DEV void sbar0() { __builtin_amdgcn_sched_barrier(0); }

typedef const __attribute__((address_space(1))) void* gp_t;
typedef __attribute__((address_space(3))) void* lp_t;

DEV void gld16(const void* g, void* l) {  // async global->LDS, 16B/lane
  __builtin_amdgcn_global_load_lds((gp_t)g, (lp_t)l, 16, 0, 0);
}

// ---------------------------------------------------------------------------
// Flat exact grid: X 4096 | Wq 512 | Wk 512 | Wv 512 | Wo 512 | mask 4 = 6148
__global__ __launch_bounds__(256) void cast_all(
    const float* __restrict__ x,
    const float* __restrict__ wq, const float* __restrict__ wk,
    const float* __restrict__ wv, const float* __restrict__ wo,
    const float* __restrict__ mask,
    unsigned short* __restrict__ xb,
    unsigned short* __restrict__ wqb, unsigned short* __restrict__ wkb,
    unsigned short* __restrict__ wvb, unsigned short* __restrict__ wob,
    float* __restrict__ emf, unsigned short* __restrict__ emb)
{
  const int cid = blockIdx.x;
  if (cid >= 6144) {  // EM = exp(mask): f32 (Vt fold) + bf16 (l-MFMA A-op)
    int i = ((cid - 6144) * 256 + (int)threadIdx.x) * 8;
    float4 a = *(const float4*)(mask + i);
    float4 b = *(const float4*)(mask + i + 4);
    const float C = 1.44269504f;
    float4 ea, eb;
    ea.x = ex2(a.x * C); ea.y = ex2(a.y * C); ea.z = ex2(a.z * C); ea.w = ex2(a.w * C);
    eb.x = ex2(b.x * C); eb.y = ex2(b.y * C); eb.z = ex2(b.z * C); eb.w = ex2(b.w * C);
    *(float4*)(emf + i) = ea;
    *(float4*)(emf + i + 4) = eb;
    u16x8_t o;
    o[0] = f2bf(ea.x); o[1] = f2bf(ea.y); o[2] = f2bf(ea.z); o[3] = f2bf(ea.w);
    o[4] = f2bf(eb.x); o[5] = f2bf(eb.y); o[6] = f2bf(eb.z); o[7] = f2bf(eb.w);
    *(u16x8_t*)(emb + i) = o;
    return;
  }
  const float* src; unsigned short* dst; int base;
  if (cid < 4096)      { src = x;  dst = xb;  base = cid; }
  else if (cid < 4608) { src = wq; dst = wqb; base = cid - 4096; }
  else if (cid < 5120) { src = wk; dst = wkb; base = cid - 4608; }
  else if (cid < 5632) { src = wv; dst = wvb; base = cid - 5120; }
  else                 { src = wo; dst = wob; base = cid - 5632; }
  int i = (base * 256 + (int)threadIdx.x) * 8;
  float4 a = *(const float4*)(src + i);
  float4 b = *(const float4*)(src + i + 4);
  u16x8_t o;
  o[0] = f2bf(a.x); o[1] = f2bf(a.y); o[2] = f2bf(a.z); o[3] = f2bf(a.w);
  o[4] = f2bf(b.x); o[5] = f2bf(b.y); o[6] = f2bf(b.z); o[7] = f2bf(b.w);
  *(u16x8_t*)(dst + i) = o;
}

// ---------------------------------------------------------------------------
// Shared GEMM body. C[m,n] = sum_k A[m,k]*B[n,k]. BM=256 x BN, BK=64, 8 waves.
// BN=128: 3-buffer lead-2 (vmcnt 6). BN=256: 2-buffer lead-1 (vmcnt 8).
// XOR-swizzled LDS (rule-21 both-sides).
// MODE 0: QK proj (z=0: Q scaled log2e/8; z=1: K), out bf16 [B,H,S,D]
// MODE 2: Vt (A=Wv rows e, B=X rows (b,s)), out bf16 [B,H,D,S] * EM (resid)
// MODE 3: WO + bias + bf16 residual (residb) -> bf16 XR [M,N]
template<int MODE, int BN>
DEV void gemm_body(char* smem, int z, int m0, int n0,
    const unsigned short* __restrict__ A,
    const unsigned short* __restrict__ B0, const unsigned short* __restrict__ B1,
    const float* __restrict__ bias0, const float* __restrict__ bias1,
    const float* __restrict__ resid, const unsigned short* __restrict__ residb,
    unsigned short* __restrict__ o0, unsigned short* __restrict__ o1,
    int K)
{
  constexpr int NBUF = (BN == 128) ? 3 : 2;      // LDS buffers
  constexpr int BTB  = BN * 128;                 // B tile bytes
  constexpr int NJ   = BN / 64;                  // n-frags per wave
  constexpr int VMN  = (BN == 128) ? 6 : 8;      // steady-state vmcnt

  const unsigned short* Bw = (MODE == 0 && z == 1) ? B1 : B0;
  const float* bias = (MODE == 0 && z == 1) ? bias1 : bias0;
  unsigned short* obf = (MODE == 0 && z == 1) ? o1 : o0;

  const int tid = threadIdx.x;
  const int lane = tid & 63;
  const int lr = lane & 15, lq = lane >> 4;
  const int wid = tid >> 6;            // 0..7
  const int wm = wid >> 2, wn = wid & 3;

  f32x4_t acc[8][NJ] = {};

  char* Abase = smem;
  char* Bbase = smem + NBUF * 32768;

  // stage K-tile kt (elements kt*64 .. +64) into buffer p
  auto STAGE = [&](int kt, int p) {
    char* ad = Abase + p * 32768;
    char* bd = Bbase + p * BTB;
    const int ke = kt * 64;
#pragma unroll
    for (int l = 0; l < 4; ++l) {      // A: 256 rows x 128 B
      int oo = tid * 16 + l * 8192;
      int row = oo >> 7, cb = oo & 127;
      int scb = cb ^ ((row & 7) << 4); // inverse swizzle on global source
      gld16((const char*)(A + (size_t)(m0 + row) * K + ke) + scb, ad + oo);
    }
#pragma unroll
    for (int l = 0; l < NJ; ++l) {     // B: BN rows x 128 B
      int oo = tid * 16 + l * 8192;
      int row = oo >> 7, cb = oo & 127;
      int scb = cb ^ ((row & 7) << 4);
      gld16((const char*)(Bw + (size_t)(n0 + row) * K + ke) + scb, bd + oo);
    }
  };

  const int NT = K >> 6;               // 16 for K=1024
  if (BN == 128) {
    STAGE(0, 0);
    STAGE(1, 1);
    wait_vm<VMN>();                    // tile 0 landed, tile 1 in flight
  } else {
    STAGE(0, 0);
    wait_vm<0>();
  }
  bar(); sbar0();

  for (int t = 0; t < NT; ++t) {
    const int p = (BN == 128) ? (t % 3) : (t & 1);
    if (BN == 128) {
      if (t + 2 < NT) { STAGE(t + 2, (t + 2) % 3); wait_vm<VMN>(); }
      else if (t == NT - 1) { wait_vm<0>(); }
      else { wait_vm<VMN>(); }
    } else {
      if (t + 1 < NT) { STAGE(t + 1, p ^ 1); wait_vm<VMN>(); }
      else { wait_vm<0>(); }
    }
    bar(); sbar0();

    const char* ab = Abase + p * 32768;
    const char* bb = Bbase + p * BTB;
#pragma unroll
    for (int ks = 0; ks < 2; ++ks) {
      bf16x8_t aF[8], bF[NJ];
#pragma unroll
      for (int i = 0; i < 8; ++i) {
        int row = wm * 128 + i * 16 + lr;
        int cc = (ks * 64 + lq * 16) ^ ((row & 7) << 4);
        aF[i] = *(const bf16x8_t*)(ab + row * 128 + cc);
      }
#pragma unroll
      for (int j = 0; j < NJ; ++j) {
        int row = wn * (16 * NJ) + j * 16 + lr;
        int cc = (ks * 64 + lq * 16) ^ ((row & 7) << 4);
        bF[j] = *(const bf16x8_t*)(bb + row * 128 + cc);
      }
#pragma unroll
      for (int i = 0; i < 8; ++i)
#pragma unroll
        for (int j = 0; j < NJ; ++j)
          acc[i][j] = __builtin_amdgcn_mfma_f32_16x16x32_bf16(aF[i], bF[j], acc[i][j], 0, 0, 0);
    }
    bar();   // all waves done reading buf p before it is restaged
  }

#pragma unroll
  for (int i = 0; i < 8; ++i) {
#pragma unroll
    for (int j = 0; j < NJ; ++j) {
      int n = n0 + wn * (16 * NJ) + j * 16 + lr;
#pragma unroll
      for (int r = 0; r < 4; ++r) {
        int m = m0 + wm * 128 + i * 16 + lq * 4 + r;
        float v = acc[i][j][r];
        if (MODE == 0) {
          // z=0 (Q): fold 1/sqrt(64) AND log2e so QK^T lands in log2 domain
          v = (v + bias[n]) * (z == 0 ? 0.18033688f : 1.0f);
          int b = m >> 11, s = m & 2047, h = n >> 6, d = n & 63;
          obf[(size_t)((b * 16 + h) * 2048 + s) * 64 + d] = f2bf(v);
        } else if (MODE == 2) {
          v = (v + bias[m]) * resid[n];  // resid = EMf, n = b*2048+s
          int b = n >> 11, s = n & 2047;
          obf[(size_t)(b * 1024 + m) * 2048 + s] = f2bf(v);
        } else {
          v = v + bias[n] + b2f(residb[(size_t)m * 1024 + n]);
          obf[(size_t)m * 1024 + n] = f2bf(v);   // bf16 XR for LN
        }
      }
    }
  }
}

// ---------------------------------------------------------------------------
// Fused QK + Vt launch: blocks 0-255 = QK (flat XCD-pair), 256-511 = Vt.
__global__ __launch_bounds__(512, 2) void gemm_qkvt(
    const unsigned short* __restrict__ Xb,
    const unsigned short* __restrict__ Wqb, const unsigned short* __restrict__ Wkb,
    const unsigned short* __restrict__ Wvb,
    const float* __restrict__ bq, const float* __restrict__ bk,
    const float* __restrict__ bv, const float* __restrict__ EMf,
    unsigned short* __restrict__ Qg, unsigned short* __restrict__ Kg,
    unsigned short* __restrict__ Vtg)
{
  __shared__ __align__(16) char smem[147456];
  const int id = blockIdx.x;
  if (id < 256) {
    // QK: flat grid 256, XCD-pair swizzle (z-pairs co-XCD for X L2 reuse)
    const int l = (id & 7) * 32 + (id >> 3);
    gemm_body<0, 256>(smem, l & 1, ((l >> 1) & 31) * 256, (l >> 6) * 256,
                      Xb, Wqb, Wkb, bq, bk, nullptr, nullptr, Qg, Kg, 1024);
  } else {
    // Vt: flat M-fast (matches dim3(4,64) dispatch order)
    const int id2 = id - 256;
    gemm_body<2, 128>(smem, 0, (id2 & 3) * 256, (id2 >> 2) * 128,
                      Wvb, Xb, nullptr, bv, nullptr, EMf, nullptr,
                      Vtg, nullptr, 1024);
  }
}

// ---------------------------------------------------------------------------
__global__ __launch_bounds__(512, 2) void gemm_wo(
    const unsigned short* __restrict__ CTX, const unsigned short* __restrict__ Wob,
    const float* __restrict__ bo, const unsigned short* __restrict__ Xb,
    unsigned short* __restrict__ XR)
{
  __shared__ __align__(16) char smem[147456];
  gemm_body<3, 128>(smem, 0, blockIdx.x * 256, blockIdx.y * 128,
                    CTX, Wob, nullptr, bo, nullptr, nullptr, Xb,
                    XR, nullptr, 1024);
}

// ---------------------------------------------------------------------------
// Flash attention, swapped-QK^T 32x32, max-free softmax, QBLK=256, KBLK=128.
// Grid 512, 256 threads (4 waves), wave owns 64 q (2 q-groups of 32).
// Counted-vmcnt pipeline; EM row (4KB) staged once in prologue. (R13 exact)
__global__ __launch_bounds__(256, 2) void attn_kernel(
    const unsigned short* __restrict__ Qg, const unsigned short* __restrict__ Kg,
    const unsigned short* __restrict__ Vtg, const unsigned short* __restrict__ EMb,
    unsigned short* __restrict__ ctx)
{
  // smem: K[2][16384] | V[2][16384] | E[4096]; epilogue reuses 0..32K
  __shared__ __align__(16) char smem[69632];

  const int id = blockIdx.x;
  const int swz = (id & 7) * 64 + (id >> 3);  // bijective XCD swizzle (512/8)
  const int bh = swz >> 3, qt = swz & 7;
  const int b = bh >> 4, h = bh & 15;

  const int tid = threadIdx.x, lane = tid & 63, wid = tid >> 6;
  const int l31 = lane & 31, hi = lane >> 5;
  const int q0 = qt * 256 + wid * 64;
  const size_t head = (size_t)bh * (2048 * 64);
  const unsigned short* Kh = Kg + head;
  const unsigned short* Vh = Vtg + (size_t)bh * 64 * 2048;
  const unsigned short* emrow = EMb + (size_t)b * 2048;

  // Q B-fragments: col q = q0 + qg*32 + l31, d = ds*16 + 8*hi + j
  bf16x8_t qf[2][4];
#pragma unroll
  for (int qg = 0; qg < 2; ++qg) {
    const unsigned short* qp = Qg + head + (size_t)(q0 + qg * 32 + l31) * 64 + 8 * hi;
#pragma unroll
    for (int ds = 0; ds < 4; ++ds) qf[qg][ds] = *(const bf16x8_t*)(qp + ds * 16);
  }

  f32x16_t oaccA[2] = {}, oaccB[2] = {};  // O^T[d,q]: d 0-31 / 32-63 per qg
  f32x16_t lacc[2] = {};                  // denominators; read [0] at end

  const int sw_row = (l31 & 7) << 4;

  // stage 128-k chunk t into buffer p: exactly 8 gloads/thread (4 K + 4 V)
  auto STAGE = [&](int t, int p) {
    const int k0 = t * 128;
    char* kd = smem + p * 16384;
    char* vd = smem + 32768 + p * 16384;
#pragma unroll
    for (int r = 0; r < 4; ++r) {
      int oo = tid * 16 + r * 4096;
      {  // K: row = k (stride 128B), inverse swizzle on source
        int row = oo >> 7, cb = oo & 127;
        int scb = cb ^ ((row & 7) << 4);
        gld16((const char*)(Kh + (size_t)(k0 + row) * 64) + scb, kd + oo);
      }
      {  // V: row = d (stride 256B), inverse swizzle on source
        int row = oo >> 8, cb = oo & 255;
        int scb = cb ^ ((row & 7) << 4);
        gld16((const char*)(Vh + (size_t)row * 2048 + k0) + scb, vd + oo);
      }
    }
  };

  // prologue: whole EM row (4KB) + tile 0; full drain once
  gld16((const char*)(emrow + tid * 8), smem + 65536 + tid * 16);
  STAGE(0, 0);
  wait_vm<0>();
  bar(); sbar0();

  for (int t = 0; t < 16; ++t) {
    const int p = t & 1;
    if (t < 15) {
      STAGE(t + 1, p ^ 1);   // 8 loads in flight across the barrier
      wait_vm<8>();          // tile t's loads complete
    } else {
      wait_vm<0>();
    }
    bar(); sbar0();

    const char* kb = smem + p * 16384;
    const char* vb = smem + 32768 + p * 16384;
    const char* eb = smem + 65536 + t * 256;

#pragma unroll
    for (int s = 0; s < 2; ++s) {  // two independent 64-k sub-tiles
      // ---- S^T = K . Q^T (log2 domain): c0 = k 0-31, c1 = k 32-63, per qg
      f32x16_t c0[2] = {}, c1[2] = {};
      {
        const char* kr0 = kb + s * 8192 + l31 * 128;
        const char* kr1 = kb + s * 8192 + (32 + l31) * 128;
        __builtin_amdgcn_s_setprio(1);
#pragma unroll
        for (int ds = 0; ds < 4; ++ds) {
          int cc = (ds * 32 + 16 * hi) ^ sw_row;
          bf16x8_t k0f = *(const bf16x8_t*)(kr0 + cc);
          bf16x8_t k1f = *(const bf16x8_t*)(kr1 + cc);
#pragma unroll
          for (int qg = 0; qg < 2; ++qg) {
            c0[qg] = __builtin_amdgcn_mfma_f32_32x32x16_bf16(k0f, qf[qg][ds], c0[qg], 0, 0, 0);
            c1[qg] = __builtin_amdgcn_mfma_f32_32x32x16_bf16(k1f, qf[qg][ds], c1[qg], 0, 0, 0);
          }
        }
        __builtin_amdgcn_s_setprio(0);
      }

      // ---- P = exp2(c) raw (max-free), pack bf16, permlane partner exchange
      bf16x8_t pf[2][4];
#pragma unroll
      for (int qg = 0; qg < 2; ++qg) {
        uint32_t w0[8], w1[8];
#pragma unroll
        for (int g = 0; g < 8; ++g) {
          const int i4 = (g & 3) * 4;
          if (g < 4) {
            w0[g] = cvtpk(ex2(c0[qg][i4]), ex2(c0[qg][i4 + 1]));
            w1[g] = cvtpk(ex2(c0[qg][i4 + 2]), ex2(c0[qg][i4 + 3]));
          } else {
            w0[g] = cvtpk(ex2(c1[qg][i4]), ex2(c1[qg][i4 + 1]));
            w1[g] = cvtpk(ex2(c1[qg][i4 + 2]), ex2(c1[qg][i4 + 3]));
          }
        }
#pragma unroll
        for (int ks = 0; ks < 4; ++ks) {
          const int gg = ((ks >> 1) << 2) + ((ks & 1) << 1);
          uint32_t a0 = w0[gg], b0 = w0[gg + 1];
          uint32_t a1 = w1[gg], b1 = w1[gg + 1];
          plswap(a0, b0);
          plswap(a1, b1);
          union { uint32_t u[4]; bf16x8_t v; } cv;
          cv.u[0] = a0; cv.u[1] = a1; cv.u[2] = b0; cv.u[3] = b1;
          pf[qg][ks] = cv.v;
        }
      }

      // ---- PV (O^T += Vt.P^T) and l (lacc += EM.P^T), frags shared across qg
      {
        const char* vr0 = vb + l31 * 256 + s * 128;
        const char* vr1 = vb + (32 + l31) * 256 + s * 128;
        const char* ebs = eb + s * 128;
        __builtin_amdgcn_s_setprio(1);
#pragma unroll
        for (int ks = 0; ks < 4; ++ks) {
          bf16x8_t ef = *(const bf16x8_t*)(ebs + ks * 32 + 16 * hi);
          int cc = (ks * 32 + 16 * hi) ^ sw_row;
          bf16x8_t v0f = *(const bf16x8_t*)(vr0 + cc);
          bf16x8_t v1f = *(const bf16x8_t*)(vr1 + cc);
#pragma unroll
          for (int qg = 0; qg < 2; ++qg) {
            oaccA[qg] = __builtin_amdgcn_mfma_f32_32x32x16_bf16(v0f, pf[qg][ks], oaccA[qg], 0, 0, 0);
            oaccB[qg] = __builtin_amdgcn_mfma_f32_32x32x16_bf16(v1f, pf[qg][ks], oaccB[qg], 0, 0, 0);
            lacc[qg]  = __builtin_amdgcn_mfma_f32_32x32x16_bf16(ef,  pf[qg][ks], lacc[qg],  0, 0, 0);
          }
        }
        __builtin_amdgcn_s_setprio(0);
      }
    }
    bar();   // all waves done reading buf p before next STAGE overwrites it
  }

  // ---- epilogue: O^T -> LDS (swizzled) -> coalesced global store
  char* tb = smem + wid * 8192;  // per-wave 64q x 128B, reuses K buffers
#pragma unroll
  for (int qg = 0; qg < 2; ++qg) {
    const float inv = 1.0f / lacc[qg][0];
    char* trow = tb + qg * 4096 + l31 * 128;
    const int swq = (l31 & 7) << 4;
#pragma unroll
    for (int g2 = 0; g2 < 4; ++g2) {
      uint2 a0, a1;
      a0.x = cvtpk(oaccA[qg][4 * g2] * inv, oaccA[qg][4 * g2 + 1] * inv);
      a0.y = cvtpk(oaccA[qg][4 * g2 + 2] * inv, oaccA[qg][4 * g2 + 3] * inv);
      a1.x = cvtpk(oaccB[qg][4 * g2] * inv, oaccB[qg][4 * g2 + 1] * inv);
      a1.y = cvtpk(oaccB[qg][4 * g2 + 2] * inv, oaccB[qg][4 * g2 + 3] * inv);
      int d0 = 16 * g2 + 8 * hi;
      *(uint2*)(trow + ((d0) ^ swq)) = a0;
      *(uint2*)(trow + ((d0 + 64) ^ swq)) = a1;
    }
  }
#pragma unroll
  for (int half = 0; half < 2; ++half) {
    const int qq = half * 32 + (lane >> 1), cp = lane & 1;
    const char* trow = tb + qq * 128;
    const int swr = (qq & 7) << 4;
    unsigned short* op = ctx + ((size_t)(b * 2048 + q0 + qq)) * 1024 + h * 64 + cp * 32;
#pragma unroll
    for (int i = 0; i < 4; ++i) {
      int col = cp * 64 + i * 16;
      u32x4_t val = *(const u32x4_t*)(trow + (col ^ swr));
      *(u32x4_t*)(op + i * 8) = val;
    }
  }
}

// ---------------------------------------------------------------------------
// LN: read bf16 XR row (2KB), stats+normalize in f32, write f32 out.
__global__ __launch_bounds__(256) void ln_kernel(
    const unsigned short* __restrict__ xr, float* __restrict__ y,
    const float* __restrict__ g, const float* __restrict__ be)
{
  const int row = blockIdx.x, tid = threadIdx.x;
  const unsigned short* rp = xr + (size_t)row * 1024;
  u16x4_t xb = *(const u16x4_t*)(rp + tid * 4);
  float4 x;
  x.x = b2f(xb[0]); x.y = b2f(xb[1]); x.z = b2f(xb[2]); x.w = b2f(xb[3]);
  float s = x.x + x.y + x.z + x.w;
  float sq = x.x * x.x + x.y * x.y + x.z * x.z + x.w * x.w;
#pragma unroll
  for (int msk = 1; msk < 64; msk <<= 1) {
    s  += __shfl_xor(s, msk);
    sq += __shfl_xor(sq, msk);
  }
  __shared__ float red[8];
  const int wid = tid >> 6, lane = tid & 63;
  if (lane == 0) { red[wid] = s; red[4 + wid] = sq; }
  __syncthreads();
  s  = red[0] + red[1] + red[2] + red[3];
  sq = red[4] + red[5] + red[6] + red[7];
  float mu = s * (1.f / 1024.f);
  float var = sq * (1.f / 1024.f) - mu * mu;
  float rs = rsqrtf(var + 1e-12f);
  float4 gw = *(const float4*)(g + tid * 4);
  float4 bw = *(const float4*)(be + tid * 4);
  float4 o2;
  o2.x = (x.x - mu) * rs * gw.x + bw.x;
  o2.y = (x.y - mu) * rs * gw.y + bw.y;
  o2.z = (x.z - mu) * rs * gw.z + bw.z;
  o2.w = (x.w - mu) * rs * gw.w + bw.w;
  *(float4*)(y + (size_t)row * 1024 + tid * 4) = o2;
}

// ---------------------------------------------------------------------------
extern "C" void kernel_launch(void* const* d_in, const int* in_sizes, int n_in,
                              void* d_out, int out_size, void* d_ws, size_t ws_size,
                              hipStream_t stream)
{
  const float* x    = (const float*)d_in[0];
  const float* mask = (const float*)d_in[1];
  const float* wq   = (const float*)d_in[2];
  const float* bq   = (const float*)d_in[3];
  const float* wk   = (const float*)d_in[4];
  const float* bk   = (const float*)d_in[5];
  const float* wv   = (const float*)d_in[6];
  const float* bv   = (const float*)d_in[7];
  const float* wo   = (const float*)d_in[8];
  const float* bo   = (const float*)d_in[9];
  const float* lnw  = (const float*)d_in[10];
  const float* lnb  = (const float*)d_in[11];
  float* out = (float*)d_out;

  char* ws = (char*)d_ws;
  unsigned short* Xb  = (unsigned short*)(ws);                               // 16 MB
  unsigned short* Wqb = (unsigned short*)(ws + 16777216);                    // 2 MB
  unsigned short* Wkb = (unsigned short*)(ws + 16777216 + 2097152);
  unsigned short* Wvb = (unsigned short*)(ws + 16777216 + 2 * 2097152);
  unsigned short* Wob = (unsigned short*)(ws + 16777216 + 3 * 2097152);
  unsigned short* Qg  = (unsigned short*)(ws + 25165824);                    // [B,H,S,D]
  unsigned short* Kg  = (unsigned short*)(ws + 25165824 + 16777216);         // [B,H,S,D]
  unsigned short* Vtg = (unsigned short*)(ws + 25165824 + 2 * 16777216);     // [B,H,D,S]
  unsigned short* CTX = (unsigned short*)(ws + 25165824 + 3 * 16777216);     // [B,S,E]
  float*          EMf = (float*)(ws + 92274688);                             // 32 KB
  unsigned short* EMb = (unsigned short*)(ws + 92274688 + 32768);            // 16 KB
  unsigned short* XR  = Xb;   // bf16 WO+resid output (Xb dead after WO reads)

  cast_all<<<dim3(6148), 256, 0, stream>>>(x, wq, wk, wv, wo, mask,
                                           Xb, Wqb, Wkb, Wvb, Wob, EMf, EMb);
  gemm_qkvt<<<dim3(512), 512, 0, stream>>>(Xb, Wqb, Wkb, Wvb, bq, bk, bv, EMf,
                                           Qg, Kg, Vtg);
  attn_kernel<<<dim3(512), 256, 0, stream>>>(Qg, Kg, Vtg, EMb, CTX);
  gemm_wo<<<dim3(32, 8), 512, 0, stream>>>(CTX, Wob, bo, Xb, XR);
  ln_kernel<<<dim3(8192), 256, 0, stream>>>(XR, out, lnw, lnb);
}

// Round 21
// 187.368 us; speedup vs baseline: 1.0397x; 1.0008x over previous
//
#include <hip/hip_runtime.h>
#include <hip/hip_bf16.h>
#include <stdint.h>

// ---------------------------------------------------------------------------
// MultiHeadSelfAttention fused block, MI355X/gfx950, bf16 MFMA pipeline.
// B=4 S=2048 E=1024 H=16 D=64.
// R20: streaming kernels (cast, LN) switched to 2048-block grid-stride (G11:
// amortize launch/setup over 3-4 iters/block). All compute kernels frozen at
// R19: fused QK+Vt (512 blocks), attn R13 (86-87us bit-stable), WO->bf16 XR,
// LN bf16-in f32-out. Total 187.5us at R19.
// ---------------------------------------------------------------------------

typedef short bf16x8_t __attribute__((ext_vector_type(8)));
typedef float f32x4_t __attribute__((ext_vector_type(4)));
typedef float f32x16_t __attribute__((ext_vector_type(16)));
typedef unsigned short u16x8_t __attribute__((ext_vector_type(8)));
typedef unsigned short u16x4_t __attribute__((ext_vector_type(4)));
typedef uint32_t u32x4_t __attribute__((ext_vector_type(4)));

#define DEV static __device__ __forceinline__

DEV unsigned short f2bf(float f) {  // RNE f32->bf16
  union { float f; uint32_t u; } v; v.f = f;
  uint32_t u = v.u;
  return (unsigned short)((u + 0x7fffu + ((u >> 16) & 1u)) >> 16);
}

DEV float b2f(unsigned short u) {
  union { uint32_t u; float f; } v; v.u = (uint32_t)u << 16; return v.f;
}

DEV uint32_t cvtpk(float a, float b) {  // packed {lo=a, hi=b} bf16, RNE
  uint32_t d;
  asm("v_cvt_pk_bf16_f32 %0, %1, %2" : "=v"(d) : "v"(a), "v"(b));
  return d;
}

// swap: a <- {a.lo_lanes, b.lo_lanes}, b <- {a.hi_lanes, b.hi_lanes}
DEV void plswap(uint32_t& a, uint32_t& b) {
  asm("v_permlane32_swap_b32 %0, %1" : "+v"(a), "+v"(b));
}

DEV float ex2(float x) { return __builtin_amdgcn_exp2f(x); }

template<int N> DEV void wait_vm() {  // counted vmem wait (T4)
  asm volatile("s_waitcnt vmcnt(%0)" :: "n"(N) : "memory");
}
DEV void bar() { __builtin_amdgcn_s_barrier(); }
DEV void sbar0() { __builtin_amdgcn_sched_barrier(0); }

typedef const __attribute__((address_space(1))) void* gp_t;
typedef __attribute__((address_space(3))) void* lp_t;

DEV void gld16(const void* g, void* l) {  // async global->LDS, 16B/lane
  __builtin_amdgcn_global_load_lds((gp_t)g, (lp_t)l, 16, 0, 0);
}

// ---------------------------------------------------------------------------
// Grid-stride cast: logical chunks X 4096 | Wq 512 | Wk 512 | Wv 512 |
// Wo 512 | mask 4 = 6148, walked by 2048 blocks.
__global__ __launch_bounds__(256) void cast_all(
    const float* __restrict__ x,
    const float* __restrict__ wq, const float* __restrict__ wk,
    const float* __restrict__ wv, const float* __restrict__ wo,
    const float* __restrict__ mask,
    unsigned short* __restrict__ xb,
    unsigned short* __restrict__ wqb, unsigned short* __restrict__ wkb,
    unsigned short* __restrict__ wvb, unsigned short* __restrict__ wob,
    float* __restrict__ emf, unsigned short* __restrict__ emb)
{
  for (int cid = blockIdx.x; cid < 6148; cid += 2048) {
    if (cid >= 6144) {  // EM = exp(mask): f32 (Vt fold) + bf16 (l-MFMA A-op)
      int i = ((cid - 6144) * 256 + (int)threadIdx.x) * 8;
      float4 a = *(const float4*)(mask + i);
      float4 b = *(const float4*)(mask + i + 4);
      const float C = 1.44269504f;
      float4 ea, eb;
      ea.x = ex2(a.x * C); ea.y = ex2(a.y * C); ea.z = ex2(a.z * C); ea.w = ex2(a.w * C);
      eb.x = ex2(b.x * C); eb.y = ex2(b.y * C); eb.z = ex2(b.z * C); eb.w = ex2(b.w * C);
      *(float4*)(emf + i) = ea;
      *(float4*)(emf + i + 4) = eb;
      u16x8_t o;
      o[0] = f2bf(ea.x); o[1] = f2bf(ea.y); o[2] = f2bf(ea.z); o[3] = f2bf(ea.w);
      o[4] = f2bf(eb.x); o[5] = f2bf(eb.y); o[6] = f2bf(eb.z); o[7] = f2bf(eb.w);
      *(u16x8_t*)(emb + i) = o;
      continue;
    }
    const float* src; unsigned short* dst; int base;
    if (cid < 4096)      { src = x;  dst = xb;  base = cid; }
    else if (cid < 4608) { src = wq; dst = wqb; base = cid - 4096; }
    else if (cid < 5120) { src = wk; dst = wkb; base = cid - 4608; }
    else if (cid < 5632) { src = wv; dst = wvb; base = cid - 5120; }
    else                 { src = wo; dst = wob; base = cid - 5632; }
    int i = (base * 256 + (int)threadIdx.x) * 8;
    float4 a = *(const float4*)(src + i);
    float4 b = *(const float4*)(src + i + 4);
    u16x8_t o;
    o[0] = f2bf(a.x); o[1] = f2bf(a.y); o[2] = f2bf(a.z); o[3] = f2bf(a.w);
    o[4] = f2bf(b.x); o[5] = f2bf(b.y); o[6] = f2bf(b.z); o[7] = f2bf(b.w);
    *(u16x8_t*)(dst + i) = o;
  }
}

// ---------------------------------------------------------------------------
// Shared GEMM body. C[m,n] = sum_k A[m,k]*B[n,k]. BM=256 x BN, BK=64, 8 waves.
// BN=128: 3-buffer lead-2 (vmcnt 6). BN=256: 2-buffer lead-1 (vmcnt 8).
// XOR-swizzled LDS (rule-21 both-sides).
// MODE 0: QK proj (z=0: Q scaled log2e/8; z=1: K), out bf16 [B,H,S,D]
// MODE 2: Vt (A=Wv rows e, B=X rows (b,s)), out bf16 [B,H,D,S] * EM (resid)
// MODE 3: WO + bias + bf16 residual (residb) -> bf16 XR [M,N]
template<int MODE, int BN>
DEV void gemm_body(char* smem, int z, int m0, int n0,
    const unsigned short* __restrict__ A,
    const unsigned short* __restrict__ B0, const unsigned short* __restrict__ B1,
    const float* __restrict__ bias0, const float* __restrict__ bias1,
    const float* __restrict__ resid, const unsigned short* __restrict__ residb,
    unsigned short* __restrict__ o0, unsigned short* __restrict__ o1,
    int K)
{
  constexpr int NBUF = (BN == 128) ? 3 : 2;      // LDS buffers
  constexpr int BTB  = BN * 128;                 // B tile bytes
  constexpr int NJ   = BN / 64;                  // n-frags per wave
  constexpr int VMN  = (BN == 128) ? 6 : 8;      // steady-state vmcnt

  const unsigned short* Bw = (MODE == 0 && z == 1) ? B1 : B0;
  const float* bias = (MODE == 0 && z == 1) ? bias1 : bias0;
  unsigned short* obf = (MODE == 0 && z == 1) ? o1 : o0;

  const int tid = threadIdx.x;
  const int lane = tid & 63;
  const int lr = lane & 15, lq = lane >> 4;
  const int wid = tid >> 6;            // 0..7
  const int wm = wid >> 2, wn = wid & 3;

  f32x4_t acc[8][NJ] = {};

  char* Abase = smem;
  char* Bbase = smem + NBUF * 32768;

  // stage K-tile kt (elements kt*64 .. +64) into buffer p
  auto STAGE = [&](int kt, int p) {
    char* ad = Abase + p * 32768;
    char* bd = Bbase + p * BTB;
    const int ke = kt * 64;
#pragma unroll
    for (int l = 0; l < 4; ++l) {      // A: 256 rows x 128 B
      int oo = tid * 16 + l * 8192;
      int row = oo >> 7, cb = oo & 127;
      int scb = cb ^ ((row & 7) << 4); // inverse swizzle on global source
      gld16((const char*)(A + (size_t)(m0 + row) * K + ke) + scb, ad + oo);
    }
#pragma unroll
    for (int l = 0; l < NJ; ++l) {     // B: BN rows x 128 B
      int oo = tid * 16 + l * 8192;
      int row = oo >> 7, cb = oo & 127;
      int scb = cb ^ ((row & 7) << 4);
      gld16((const char*)(Bw + (size_t)(n0 + row) * K + ke) + scb, bd + oo);
    }
  };

  const int NT = K >> 6;               // 16 for K=1024
  if (BN == 128) {
    STAGE(0, 0);
    STAGE(1, 1);
    wait_vm<VMN>();                    // tile 0 landed, tile 1 in flight
  } else {
    STAGE(0, 0);
    wait_vm<0>();
  }
  bar(); sbar0();

  for (int t = 0; t < NT; ++t) {
    const int p = (BN == 128) ? (t % 3) : (t & 1);
    if (BN == 128) {
      if (t + 2 < NT) { STAGE(t + 2, (t + 2) % 3); wait_vm<VMN>(); }
      else if (t == NT - 1) { wait_vm<0>(); }
      else { wait_vm<VMN>(); }
    } else {
      if (t + 1 < NT) { STAGE(t + 1, p ^ 1); wait_vm<VMN>(); }
      else { wait_vm<0>(); }
    }
    bar(); sbar0();

    const char* ab = Abase + p * 32768;
    const char* bb = Bbase + p * BTB;
#pragma unroll
    for (int ks = 0; ks < 2; ++ks) {
      bf16x8_t aF[8], bF[NJ];
#pragma unroll
      for (int i = 0; i < 8; ++i) {
        int row = wm * 128 + i * 16 + lr;
        int cc = (ks * 64 + lq * 16) ^ ((row & 7) << 4);
        aF[i] = *(const bf16x8_t*)(ab + row * 128 + cc);
      }
#pragma unroll
      for (int j = 0; j < NJ; ++j) {
        int row = wn * (16 * NJ) + j * 16 + lr;
        int cc = (ks * 64 + lq * 16) ^ ((row & 7) << 4);
        bF[j] = *(const bf16x8_t*)(bb + row * 128 + cc);
      }
#pragma unroll
      for (int i = 0; i < 8; ++i)
#pragma unroll
        for (int j = 0; j < NJ; ++j)
          acc[i][j] = __builtin_amdgcn_mfma_f32_16x16x32_bf16(aF[i], bF[j], acc[i][j], 0, 0, 0);
    }
    bar();   // all waves done reading buf p before it is restaged
  }

#pragma unroll
  for (int i = 0; i < 8; ++i) {
#pragma unroll
    for (int j = 0; j < NJ; ++j) {
      int n = n0 + wn * (16 * NJ) + j * 16 + lr;
#pragma unroll
      for (int r = 0; r < 4; ++r) {
        int m = m0 + wm * 128 + i * 16 + lq * 4 + r;
        float v = acc[i][j][r];
        if (MODE == 0) {
          // z=0 (Q): fold 1/sqrt(64) AND log2e so QK^T lands in log2 domain
          v = (v + bias[n]) * (z == 0 ? 0.18033688f : 1.0f);
          int b = m >> 11, s = m & 2047, h = n >> 6, d = n & 63;
          obf[(size_t)((b * 16 + h) * 2048 + s) * 64 + d] = f2bf(v);
        } else if (MODE == 2) {
          v = (v + bias[m]) * resid[n];  // resid = EMf, n = b*2048+s
          int b = n >> 11, s = n & 2047;
          obf[(size_t)(b * 1024 + m) * 2048 + s] = f2bf(v);
        } else {
          v = v + bias[n] + b2f(residb[(size_t)m * 1024 + n]);
          obf[(size_t)m * 1024 + n] = f2bf(v);   // bf16 XR for LN
        }
      }
    }
  }
}

// ---------------------------------------------------------------------------
// Fused QK + Vt launch: blocks 0-255 = QK (flat XCD-pair), 256-511 = Vt.
__global__ __launch_bounds__(512, 2) void gemm_qkvt(
    const unsigned short* __restrict__ Xb,
    const unsigned short* __restrict__ Wqb, const unsigned short* __restrict__ Wkb,
    const unsigned short* __restrict__ Wvb,
    const float* __restrict__ bq, const float* __restrict__ bk,
    const float* __restrict__ bv, const float* __restrict__ EMf,
    unsigned short* __restrict__ Qg, unsigned short* __restrict__ Kg,
    unsigned short* __restrict__ Vtg)
{
  __shared__ __align__(16) char smem[147456];
  const int id = blockIdx.x;
  if (id < 256) {
    // QK: flat grid 256, XCD-pair swizzle (z-pairs co-XCD for X L2 reuse)
    const int l = (id & 7) * 32 + (id >> 3);
    gemm_body<0, 256>(smem, l & 1, ((l >> 1) & 31) * 256, (l >> 6) * 256,
                      Xb, Wqb, Wkb, bq, bk, nullptr, nullptr, Qg, Kg, 1024);
  } else {
    // Vt: flat M-fast (matches dim3(4,64) dispatch order)
    const int id2 = id - 256;
    gemm_body<2, 128>(smem, 0, (id2 & 3) * 256, (id2 >> 2) * 128,
                      Wvb, Xb, nullptr, bv, nullptr, EMf, nullptr,
                      Vtg, nullptr, 1024);
  }
}

// ---------------------------------------------------------------------------
__global__ __launch_bounds__(512, 2) void gemm_wo(
    const unsigned short* __restrict__ CTX, const unsigned short* __restrict__ Wob,
    const float* __restrict__ bo, const unsigned short* __restrict__ Xb,
    unsigned short* __restrict__ XR)
{
  __shared__ __align__(16) char smem[147456];
  gemm_body<3, 128>(smem, 0, blockIdx.x * 256, blockIdx.y * 128,
                    CTX, Wob, nullptr, bo, nullptr, nullptr, Xb,
                    XR, nullptr, 1024);
}

// ---------------------------------------------------------------------------
// Flash attention, swapped-QK^T 32x32, max-free softmax, QBLK=256, KBLK=128.
// Grid 512, 256 threads (4 waves), wave owns 64 q (2 q-groups of 32).
// Counted-vmcnt pipeline; EM row (4KB) staged once in prologue. (R13 exact)
__global__ __launch_bounds__(256, 2) void attn_kernel(
    const unsigned short* __restrict__ Qg, const unsigned short* __restrict__ Kg,
    const unsigned short* __restrict__ Vtg, const unsigned short* __restrict__ EMb,
    unsigned short* __restrict__ ctx)
{
  // smem: K[2][16384] | V[2][16384] | E[4096]; epilogue reuses 0..32K
  __shared__ __align__(16) char smem[69632];

  const int id = blockIdx.x;
  const int swz = (id & 7) * 64 + (id >> 3);  // bijective XCD swizzle (512/8)
  const int bh = swz >> 3, qt = swz & 7;
  const int b = bh >> 4, h = bh & 15;

  const int tid = threadIdx.x, lane = tid & 63, wid = tid >> 6;
  const int l31 = lane & 31, hi = lane >> 5;
  const int q0 = qt * 256 + wid * 64;
  const size_t head = (size_t)bh * (2048 * 64);
  const unsigned short* Kh = Kg + head;
  const unsigned short* Vh = Vtg + (size_t)bh * 64 * 2048;
  const unsigned short* emrow = EMb + (size_t)b * 2048;

  // Q B-fragments: col q = q0 + qg*32 + l31, d = ds*16 + 8*hi + j
  bf16x8_t qf[2][4];
#pragma unroll
  for (int qg = 0; qg < 2; ++qg) {
    const unsigned short* qp = Qg + head + (size_t)(q0 + qg * 32 + l31) * 64 + 8 * hi;
#pragma unroll
    for (int ds = 0; ds < 4; ++ds) qf[qg][ds] = *(const bf16x8_t*)(qp + ds * 16);
  }

  f32x16_t oaccA[2] = {}, oaccB[2] = {};  // O^T[d,q]: d 0-31 / 32-63 per qg
  f32x16_t lacc[2] = {};                  // denominators; read [0] at end

  const int sw_row = (l31 & 7) << 4;

  // stage 128-k chunk t into buffer p: exactly 8 gloads/thread (4 K + 4 V)
  auto STAGE = [&](int t, int p) {
    const int k0 = t * 128;
    char* kd = smem + p * 16384;
    char* vd = smem + 32768 + p * 16384;
#pragma unroll
    for (int r = 0; r < 4; ++r) {
      int oo = tid * 16 + r * 4096;
      {  // K: row = k (stride 128B), inverse swizzle on source
        int row = oo >> 7, cb = oo & 127;
        int scb = cb ^ ((row & 7) << 4);
        gld16((const char*)(Kh + (size_t)(k0 + row) * 64) + scb, kd + oo);
      }
      {  // V: row = d (stride 256B), inverse swizzle on source
        int row = oo >> 8, cb = oo & 255;
        int scb = cb ^ ((row & 7) << 4);
        gld16((const char*)(Vh + (size_t)row * 2048 + k0) + scb, vd + oo);
      }
    }
  };

  // prologue: whole EM row (4KB) + tile 0; full drain once
  gld16((const char*)(emrow + tid * 8), smem + 65536 + tid * 16);
  STAGE(0, 0);
  wait_vm<0>();
  bar(); sbar0();

  for (int t = 0; t < 16; ++t) {
    const int p = t & 1;
    if (t < 15) {
      STAGE(t + 1, p ^ 1);   // 8 loads in flight across the barrier
      wait_vm<8>();          // tile t's loads complete
    } else {
      wait_vm<0>();
    }
    bar(); sbar0();

    const char* kb = smem + p * 16384;
    const char* vb = smem + 32768 + p * 16384;
    const char* eb = smem + 65536 + t * 256;

#pragma unroll
    for (int s = 0; s < 2; ++s) {  // two independent 64-k sub-tiles
      // ---- S^T = K . Q^T (log2 domain): c0 = k 0-31, c1 = k 32-63, per qg
      f32x16_t c0[2] = {}, c1[2] = {};
      {
        const char* kr0 = kb + s * 8192 + l31 * 128;
        const char* kr1 = kb + s * 8192 + (32 + l31) * 128;
        __builtin_amdgcn_s_setprio(1);
#pragma unroll
        for (int ds = 0; ds < 4; ++ds) {
          int cc = (ds * 32 + 16 * hi) ^ sw_row;
          bf16x8_t k0f = *(const bf16x8_t*)(kr0 + cc);
          bf16x8_t k1f = *(const bf16x8_t*)(kr1 + cc);
#pragma unroll
          for (int qg = 0; qg < 2; ++qg) {
            c0[qg] = __builtin_amdgcn_mfma_f32_32x32x16_bf16(k0f, qf[qg][ds], c0[qg], 0, 0, 0);
            c1[qg] = __builtin_amdgcn_mfma_f32_32x32x16_bf16(k1f, qf[qg][ds], c1[qg], 0, 0, 0);
          }
        }
        __builtin_amdgcn_s_setprio(0);
      }

      // ---- P = exp2(c) raw (max-free), pack bf16, permlane partner exchange
      bf16x8_t pf[2][4];
#pragma unroll
      for (int qg = 0; qg < 2; ++qg) {
        uint32_t w0[8], w1[8];
#pragma unroll
        for (int g = 0; g < 8; ++g) {
          const int i4 = (g & 3) * 4;
          if (g < 4) {
            w0[g] = cvtpk(ex2(c0[qg][i4]), ex2(c0[qg][i4 + 1]));
            w1[g] = cvtpk(ex2(c0[qg][i4 + 2]), ex2(c0[qg][i4 + 3]));
          } else {
            w0[g] = cvtpk(ex2(c1[qg][i4]), ex2(c1[qg][i4 + 1]));
            w1[g] = cvtpk(ex2(c1[qg][i4 + 2]), ex2(c1[qg][i4 + 3]));
          }
        }
#pragma unroll
        for (int ks = 0; ks < 4; ++ks) {
          const int gg = ((ks >> 1) << 2) + ((ks & 1) << 1);
          uint32_t a0 = w0[gg], b0 = w0[gg + 1];
          uint32_t a1 = w1[gg], b1 = w1[gg + 1];
          plswap(a0, b0);
          plswap(a1, b1);
          union { uint32_t u[4]; bf16x8_t v; } cv;
          cv.u[0] = a0; cv.u[1] = a1; cv.u[2] = b0; cv.u[3] = b1;
          pf[qg][ks] = cv.v;
        }
      }

      // ---- PV (O^T += Vt.P^T) and l (lacc += EM.P^T), frags shared across qg
      {
        const char* vr0 = vb + l31 * 256 + s * 128;
        const char* vr1 = vb + (32 + l31) * 256 + s * 128;
        const char* ebs = eb + s * 128;
        __builtin_amdgcn_s_setprio(1);
#pragma unroll
        for (int ks = 0; ks < 4; ++ks) {
          bf16x8_t ef = *(const bf16x8_t*)(ebs + ks * 32 + 16 * hi);
          int cc = (ks * 32 + 16 * hi) ^ sw_row;
          bf16x8_t v0f = *(const bf16x8_t*)(vr0 + cc);
          bf16x8_t v1f = *(const bf16x8_t*)(vr1 + cc);
#pragma unroll
          for (int qg = 0; qg < 2; ++qg) {
            oaccA[qg] = __builtin_amdgcn_mfma_f32_32x32x16_bf16(v0f, pf[qg][ks], oaccA[qg], 0, 0, 0);
            oaccB[qg] = __builtin_amdgcn_mfma_f32_32x32x16_bf16(v1f, pf[qg][ks], oaccB[qg], 0, 0, 0);
            lacc[qg]  = __builtin_amdgcn_mfma_f32_32x32x16_bf16(ef,  pf[qg][ks], lacc[qg],  0, 0, 0);
          }
        }
        __builtin_amdgcn_s_setprio(0);
      }
    }
    bar();   // all waves done reading buf p before next STAGE overwrites it
  }

  // ---- epilogue: O^T -> LDS (swizzled) -> coalesced global store
  char* tb = smem + wid * 8192;  // per-wave 64q x 128B, reuses K buffers
#pragma unroll
  for (int qg = 0; qg < 2; ++qg) {
    const float inv = 1.0f / lacc[qg][0];
    char* trow = tb + qg * 4096 + l31 * 128;
    const int swq = (l31 & 7) << 4;
#pragma unroll
    for (int g2 = 0; g2 < 4; ++g2) {
      uint2 a0, a1;
      a0.x = cvtpk(oaccA[qg][4 * g2] * inv, oaccA[qg][4 * g2 + 1] * inv);
      a0.y = cvtpk(oaccA[qg][4 * g2 + 2] * inv, oaccA[qg][4 * g2 + 3] * inv);
      a1.x = cvtpk(oaccB[qg][4 * g2] * inv, oaccB[qg][4 * g2 + 1] * inv);
      a1.y = cvtpk(oaccB[qg][4 * g2 + 2] * inv, oaccB[qg][4 * g2 + 3] * inv);
      int d0 = 16 * g2 + 8 * hi;
      *(uint2*)(trow + ((d0) ^ swq)) = a0;
      *(uint2*)(trow + ((d0 + 64) ^ swq)) = a1;
    }
  }
#pragma unroll
  for (int half = 0; half < 2; ++half) {
    const int qq = half * 32 + (lane >> 1), cp = lane & 1;
    const char* trow = tb + qq * 128;
    const int swr = (qq & 7) << 4;
    unsigned short* op = ctx + ((size_t)(b * 2048 + q0 + qq)) * 1024 + h * 64 + cp * 32;
#pragma unroll
    for (int i = 0; i < 4; ++i) {
      int col = cp * 64 + i * 16;
      u32x4_t val = *(const u32x4_t*)(trow + (col ^ swr));
      *(u32x4_t*)(op + i * 8) = val;
    }
  }
}

// ---------------------------------------------------------------------------
// Grid-stride LN: 2048 blocks x 4 rows. Read bf16 XR, stats/normalize f32.
__global__ __launch_bounds__(256) void ln_kernel(
    const unsigned short* __restrict__ xr, float* __restrict__ y,
    const float* __restrict__ g, const float* __restrict__ be)
{
  const int tid = threadIdx.x;
  const int wid = tid >> 6, lane = tid & 63;
  __shared__ float red[8];
  const float4 gw = *(const float4*)(g + tid * 4);
  const float4 bw = *(const float4*)(be + tid * 4);

  for (int row = blockIdx.x; row < 8192; row += 2048) {
    const unsigned short* rp = xr + (size_t)row * 1024;
    u16x4_t xb = *(const u16x4_t*)(rp + tid * 4);
    float4 x;
    x.x = b2f(xb[0]); x.y = b2f(xb[1]); x.z = b2f(xb[2]); x.w = b2f(xb[3]);
    float s = x.x + x.y + x.z + x.w;
    float sq = x.x * x.x + x.y * x.y + x.z * x.z + x.w * x.w;
#pragma unroll
    for (int msk = 1; msk < 64; msk <<= 1) {
      s  += __shfl_xor(s, msk);
      sq += __shfl_xor(sq, msk);
    }
    if (lane == 0) { red[wid] = s; red[4 + wid] = sq; }
    __syncthreads();
    s  = red[0] + red[1] + red[2] + red[3];
    sq = red[4] + red[5] + red[6] + red[7];
    float mu = s * (1.f / 1024.f);
    float var = sq * (1.f / 1024.f) - mu * mu;
    float rs = rsqrtf(var + 1e-12f);
    float4 o2;
    o2.x = (x.x - mu) * rs * gw.x + bw.x;
    o2.y = (x.y - mu) * rs * gw.y + bw.y;
    o2.z = (x.z - mu) * rs * gw.z + bw.z;
    o2.w = (x.w - mu) * rs * gw.w + bw.w;
    *(float4*)(y + (size_t)row * 1024 + tid * 4) = o2;
    __syncthreads();   // red[] safe for next row
  }
}

// ---------------------------------------------------------------------------
extern "C" void kernel_launch(void* const* d_in, const int* in_sizes, int n_in,
                              void* d_out, int out_size, void* d_ws, size_t ws_size,
                              hipStream_t stream)
{
  const float* x    = (const float*)d_in[0];
  const float* mask = (const float*)d_in[1];
  const float* wq   = (const float*)d_in[2];
  const float* bq   = (const float*)d_in[3];
  const float* wk   = (const float*)d_in[4];
  const float* bk   = (const float*)d_in[5];
  const float* wv   = (const float*)d_in[6];
  const float* bv   = (const float*)d_in[7];
  const float* wo   = (const float*)d_in[8];
  const float* bo   = (const float*)d_in[9];
  const float* lnw  = (const float*)d_in[10];
  const float* lnb  = (const float*)d_in[11];
  float* out = (float*)d_out;

  char* ws = (char*)d_ws;
  unsigned short* Xb  = (unsigned short*)(ws);                               // 16 MB
  unsigned short* Wqb = (unsigned short*)(ws + 16777216);                    // 2 MB
  unsigned short* Wkb = (unsigned short*)(ws + 16777216 + 2097152);
  unsigned short* Wvb = (unsigned short*)(ws + 16777216 + 2 * 2097152);
  unsigned short* Wob = (unsigned short*)(ws + 16777216 + 3 * 2097152);
  unsigned short* Qg  = (unsigned short*)(ws + 25165824);                    // [B,H,S,D]
  unsigned short* Kg  = (unsigned short*)(ws + 25165824 + 16777216);         // [B,H,S,D]
  unsigned short* Vtg = (unsigned short*)(ws + 25165824 + 2 * 16777216);     // [B,H,D,S]
  unsigned short* CTX = (unsigned short*)(ws + 25165824 + 3 * 16777216);     // [B,S,E]
  float*          EMf = (float*)(ws + 92274688);                             // 32 KB
  unsigned short* EMb = (unsigned short*)(ws + 92274688 + 32768);            // 16 KB
  unsigned short* XR  = Xb;   // bf16 WO+resid output (Xb dead after WO reads)

  cast_all<<<dim3(2048), 256, 0, stream>>>(x, wq, wk, wv, wo, mask,
                                           Xb, Wqb, Wkb, Wvb, Wob, EMf, EMb);
  gemm_qkvt<<<dim3(512), 512, 0, stream>>>(Xb, Wqb, Wkb, Wvb, bq, bk, bv, EMf,
                                           Qg, Kg, Vtg);
  attn_kernel<<<dim3(512), 256, 0, stream>>>(Qg, Kg, Vtg, EMb, CTX);
  gemm_wo<<<dim3(32, 8), 512, 0, stream>>>(CTX, Wob, bo, Xb, XR);
  ln_kernel<<<dim3(2048), 256, 0, stream>>>(XR, out, lnw, lnb);
}